// Round 7
// baseline (242.758 us; speedup 1.0000x reference)
//
#include <hip/hip_runtime.h>
#include <hip/hip_fp16.h>
#include <cstdint>
#include <cstring>

typedef unsigned int uint;

#define BSHIFT 8          // 256 nodes per bucket
#define NBUCK 512         // max buckets (N up to 131072)
#define TILE 4096         // kb_scatter tile
#define SCAT_T 512
#define SORT_T 512
#define SORT_CAP 5120     // per-bucket capacity (mean ~4092, +16 sigma)

__device__ __forceinline__ float leaky02(float x) { return x > 0.f ? x : 0.2f * x; }
__device__ __forceinline__ float bflo(uint u) { return __uint_as_float(u << 16); }
__device__ __forceinline__ float bfhi(uint u) { return __uint_as_float(u & 0xffff0000u); }

__device__ __forceinline__ uint pack_bf16x2(float a, float b) {
    uint ua = __float_as_uint(a), ub = __float_as_uint(b);
    ua += 0x7fffu + ((ua >> 16) & 1u);
    ub += 0x7fffu + ((ub >> 16) & 1u);
    return (ua >> 16) | (ub & 0xffff0000u);
}

__device__ __forceinline__ uint packh2(float a, float b) {
    __half ha = __float2half_rn(a), hb = __float2half_rn(b);
    unsigned short ua, ub;
    memcpy(&ua, &ha, 2);
    memcpy(&ub, &hb, 2);
    return (uint)ua | ((uint)ub << 16);
}

// ---------------------------------------------------------------------------
// Kernel A: h = x @ W_lin (bf16x2); a_src/a_dst via per-block computed 16x4
// Ws/Wd (folded from the old k_prep — 64 threads x 64 FMAs, bit-identical).
// Block 0 additionally zeroes cursor/sums/sumsq (stream-ordered before
// kb_scatter / k_bnstats consume them). One launch fewer.
// ---------------------------------------------------------------------------
__global__ void k_linear(const float* __restrict__ x, const float* __restrict__ W,
                         const float* __restrict__ att_s, const float* __restrict__ att_d,
                         uint* __restrict__ h, float* __restrict__ a_src,
                         float* __restrict__ a_dst, int* __restrict__ cursor,
                         float* __restrict__ sums, float* __restrict__ sumsq, int N) {
    int tid = threadIdx.x;  // 256
    __shared__ float sx[32][16];
    __shared__ float sWs[64], sWd[64];
    int j = tid & 63;       // channel pair
    int sub = tid >> 6;     // wave id -> node subgroup
    int n0 = blockIdx.x * 32;

    if (blockIdx.x == 0) {
        cursor[tid] = 0; cursor[tid + 256] = 0;
        if (tid < 128) sums[tid] = 0.f;
        else sumsq[tid - 128] = 0.f;
    }

    float2 wreg[16];
#pragma unroll
    for (int k = 0; k < 16; k++) wreg[k] = ((const float2*)(W + k * 128))[j];

    if (tid < 128) {
        int row = tid >> 2;
        if (n0 + row < N)
            ((float4*)sx)[tid] = ((const float4*)(x + (size_t)n0 * 16))[tid];
    } else if (tid < 192) {
        int t = tid - 128;              // t = k*4 + hh
        int k = t >> 2, hh = t & 3;
        float s1 = 0.f, s2 = 0.f;
        for (int c = 0; c < 32; c++) {
            float wv = W[k * 128 + hh * 32 + c];
            s1 += wv * att_s[hh * 32 + c];
            s2 += wv * att_d[hh * 32 + c];
        }
        sWs[t] = s1;
        sWd[t] = s2;
    }
    __syncthreads();

#pragma unroll
    for (int i = 0; i < 8; i++) {
        int loc = sub + i * 4;
        int n = n0 + loc;
        if (n >= N) break;
        float acc0 = 0.f, acc1 = 0.f;
#pragma unroll
        for (int k = 0; k < 16; k++) {
            float xk = sx[loc][k];
            acc0 += xk * wreg[k].x;
            acc1 += xk * wreg[k].y;
        }
        h[(size_t)n * 64 + j] = pack_bf16x2(acc0, acc1);
    }

    // a_src / a_dst: thread t -> (node tid>>3, head (tid>>1)&3, sd tid&1)
    int loc2 = tid >> 3, hh = (tid >> 1) & 3, sd = tid & 1;
    int n2 = n0 + loc2;
    if (n2 < N) {
        const float* Wm = sd ? sWd : sWs;
        float acc = 0.f;
#pragma unroll
        for (int k = 0; k < 16; k++) acc += sx[loc2][k] * Wm[k * 4 + hh];
        if (sd) a_dst[n2 * 4 + hh] = acc;
        else    a_src[n2 * 4 + hh] = acc;
    }
}

// ---------------------------------------------------------------------------
// Scatter into capacity buckets: bucket b owns pairs[b*SORT_CAP ...].
// LDS-staged dense writes; wave-shfl scan (2 barriers instead of ~18).
// code = (src<<8)|(dst&255).
// ---------------------------------------------------------------------------
__global__ void kb_scatter(const int* __restrict__ src, const int* __restrict__ dst, int E,
                           int* __restrict__ cursor, uint* __restrict__ pairs) {
    __shared__ int tileCnt[NBUCK], tileCnt2[NBUCK], tileOff[NBUCK], gbase[NBUCK];
    __shared__ int wsum[8], wbase[8];
    __shared__ uint lp[TILE];
    __shared__ unsigned short lb[TILE];
    int tid = threadIdx.x;  // 512
    int l = tid & 63, w = tid >> 6;
    int t0 = blockIdx.x * TILE;
    tileCnt[tid] = 0;
    tileCnt2[tid] = 0;
    __syncthreads();
    int dreg[8], sreg[8];
#pragma unroll
    for (int j = 0; j < 8; j++) {
        int idx = t0 + j * SCAT_T + tid;
        if (idx < E) {
            dreg[j] = dst[idx];
            sreg[j] = src[idx];
            atomicAdd(&tileCnt[dreg[j] >> BSHIFT], 1);
        } else dreg[j] = -1;
    }
    __syncthreads();
    // wave-shfl exclusive scan over 512 entries
    int v = tileCnt[tid];
    int s = v;
#pragma unroll
    for (int off = 1; off < 64; off <<= 1) {
        int t = __shfl_up(s, off);
        if (l >= off) s += t;
    }
    if (l == 63) wsum[w] = s;
    __syncthreads();
    if (tid < 8) {
        int b = 0;
        for (int i = 0; i < tid; i++) b += wsum[i];
        wbase[tid] = b;
    }
    __syncthreads();
    int ex = s - v + wbase[w];
    tileOff[tid] = ex;
    if (v > 0) gbase[tid] = atomicAdd(&cursor[tid], v);
    __syncthreads();
#pragma unroll
    for (int j = 0; j < 8; j++) {
        if (dreg[j] >= 0) {
            int bk = dreg[j] >> BSHIFT;
            int r = atomicAdd(&tileCnt2[bk], 1);
            int pos = tileOff[bk] + r;
            lp[pos] = ((uint)sreg[j] << BSHIFT) | (uint)(dreg[j] & 255);
            lb[pos] = (unsigned short)bk;
        }
    }
    __syncthreads();
    int tot = min(TILE, E - t0);
    for (int k = tid; k < tot; k += SCAT_T) {
        int bk = lb[k];
        int lpos = gbase[bk] + (k - tileOff[bk]);
        if (lpos < SORT_CAP)
            pairs[(size_t)bk * SORT_CAP + lpos] = lp[k];
    }
}

// ---------------------------------------------------------------------------
// Per-bucket counting sort + per-edge weight precompute.
// Wave-shfl scan; emits sorted[] (src) and wsorted[] (fp16x4), coalesced.
// ---------------------------------------------------------------------------
__global__ void kb_sort(const uint* __restrict__ pairs, const int* __restrict__ cursor,
                        const float* __restrict__ a_src, const float* __restrict__ a_dst,
                        int N,
                        int* __restrict__ sorted, uint2* __restrict__ wsorted,
                        int* __restrict__ offsets, int* __restrict__ degs) {
    __shared__ int cnt[256], off0[256];
    __shared__ int wsum[4], wbase[4];
    __shared__ uint lcode[SORT_CAP];
    __shared__ float4 sad[256];
    int tid = threadIdx.x;  // 512
    int l = tid & 63, w = tid >> 6;
    int b = blockIdx.x;
    int n0 = b << BSHIFT;
    int nn = min(256, N - n0);
    int ebase = b * SORT_CAP;
    int ecnt = cursor[b];
    if (ecnt > SORT_CAP) ecnt = SORT_CAP;
    if (tid < 256) cnt[tid] = 0;
    if (tid < nn) sad[tid] = ((const float4*)a_dst)[n0 + tid];
    __syncthreads();
    for (int k = tid; k < ecnt; k += SORT_T)
        atomicAdd(&cnt[pairs[ebase + k] & 255], 1);
    __syncthreads();
    // wave-shfl exclusive scan over 256 entries (waves 0..3)
    int v = (tid < 256) ? cnt[tid] : 0;
    int s = v;
#pragma unroll
    for (int off = 1; off < 64; off <<= 1) {
        int t = __shfl_up(s, off);
        if (l >= off) s += t;
    }
    if (tid < 256 && l == 63) wsum[w] = s;
    __syncthreads();
    if (tid < 4) {
        int base = 0;
        for (int i = 0; i < tid; i++) base += wsum[i];
        wbase[tid] = base;
    }
    __syncthreads();
    if (tid < 256) off0[tid] = s - v + wbase[w];
    __syncthreads();
    if (tid < 256) cnt[tid] = 0;
    __syncthreads();
    for (int k = tid; k < ecnt; k += SORT_T) {
        uint p = pairs[ebase + k];
        int ln = p & 255;
        int r = atomicAdd(&cnt[ln], 1);
        lcode[off0[ln] + r] = p;
    }
    __syncthreads();
    // pass 2: in-order, fully coalesced emit
    for (int k = tid; k < ecnt; k += SORT_T) {
        uint p = lcode[k];
        int src = (int)(p >> BSHIFT);
        int ln = p & 255;
        sorted[ebase + k] = src;
        float4 as = ((const float4*)a_src)[src];
        float4 ad = sad[ln];
        float w0 = __expf(leaky02(as.x + ad.x));
        float w1 = __expf(leaky02(as.y + ad.y));
        float w2 = __expf(leaky02(as.z + ad.z));
        float w3 = __expf(leaky02(as.w + ad.w));
        wsorted[ebase + k] = make_uint2(packh2(w0, w1), packh2(w2, w3));
    }
    if (tid < nn) {
        offsets[n0 + tid] = ebase + off0[tid];
        degs[n0 + tid] = v;
    }
}

// ---------------------------------------------------------------------------
// GAT aggregation: 4 nodes per wave, 16 lanes per node (8 ch/lane, uint4).
// At the ~3.55 TB/s random-gather TCC ceiling with ~8x XCD-replicated h
// traffic (202 MB ~= floor for uniform-random graph). fp8 h failed the
// precision budget (R5: absmax 0.043 > 0.021); bf16 is the floor dtype.
// ---------------------------------------------------------------------------
__global__ void k_gat(const int* __restrict__ offsets, const int* __restrict__ degs,
                      const int* __restrict__ sorted, const uint2* __restrict__ wsorted,
                      const uint* __restrict__ h, const float* __restrict__ a_src,
                      const float* __restrict__ a_dst, const float* __restrict__ bias,
                      uint* __restrict__ hagg, int N) {
    int nb = gridDim.x;
    int g = nb >> 3;
    int bi = blockIdx.x;
    int blk = (bi < (g << 3)) ? ((bi & 7) * g + (bi >> 3)) : bi;
    int lane = threadIdx.x & 63;
    int wid = threadIdx.x >> 6;
    int q = lane >> 4;
    int l16 = lane & 15;
    int head = l16 >> 2;
    int d = blk * 16 + wid * 4 + q;
    if (d >= N) return;
    int base = offsets[d];
    int deg = degs[d];

    const int* sp = sorted + base;
    const __half* wp = (const __half*)(wsorted + base) + head;

    float w = __expf(leaky02(a_src[d * 4 + head] + a_dst[d * 4 + head]));
    uint4 u = ((const uint4*)(h + (size_t)d * 64))[l16];
    float sum = w;
    float2 a01 = make_float2(w * bflo(u.x), w * bfhi(u.x));
    float2 a23 = make_float2(w * bflo(u.y), w * bfhi(u.y));
    float2 a45 = make_float2(w * bflo(u.z), w * bfhi(u.z));
    float2 a67 = make_float2(w * bflo(u.w), w * bfhi(u.w));

    int i = 0;
    for (; i + 3 < deg; i += 4) {
        int s0 = sp[i];
        int s1 = sp[i + 1];
        int s2 = sp[i + 2];
        int s3 = sp[i + 3];
        float w0 = __half2float(wp[i * 4]);
        float w1 = __half2float(wp[(i + 1) * 4]);
        float w2 = __half2float(wp[(i + 2) * 4]);
        float w3 = __half2float(wp[(i + 3) * 4]);
        uint4 u0 = ((const uint4*)(h + (size_t)s0 * 64))[l16];
        uint4 u1 = ((const uint4*)(h + (size_t)s1 * 64))[l16];
        uint4 u2 = ((const uint4*)(h + (size_t)s2 * 64))[l16];
        uint4 u3 = ((const uint4*)(h + (size_t)s3 * 64))[l16];
        sum += (w0 + w1) + (w2 + w3);
        float2 w02 = {w0, w0}, w12 = {w1, w1}, w22 = {w2, w2}, w32 = {w3, w3};
        a01 += make_float2(bflo(u0.x), bfhi(u0.x)) * w02
             + make_float2(bflo(u1.x), bfhi(u1.x)) * w12
             + make_float2(bflo(u2.x), bfhi(u2.x)) * w22
             + make_float2(bflo(u3.x), bfhi(u3.x)) * w32;
        a23 += make_float2(bflo(u0.y), bfhi(u0.y)) * w02
             + make_float2(bflo(u1.y), bfhi(u1.y)) * w12
             + make_float2(bflo(u2.y), bfhi(u2.y)) * w22
             + make_float2(bflo(u3.y), bfhi(u3.y)) * w32;
        a45 += make_float2(bflo(u0.z), bfhi(u0.z)) * w02
             + make_float2(bflo(u1.z), bfhi(u1.z)) * w12
             + make_float2(bflo(u2.z), bfhi(u2.z)) * w22
             + make_float2(bflo(u3.z), bfhi(u3.z)) * w32;
        a67 += make_float2(bflo(u0.w), bfhi(u0.w)) * w02
             + make_float2(bflo(u1.w), bfhi(u1.w)) * w12
             + make_float2(bflo(u2.w), bfhi(u2.w)) * w22
             + make_float2(bflo(u3.w), bfhi(u3.w)) * w32;
    }
    for (; i < deg; i++) {
        int s0 = sp[i];
        float w0 = __half2float(wp[i * 4]);
        uint4 u0 = ((const uint4*)(h + (size_t)s0 * 64))[l16];
        sum += w0;
        float2 w02 = {w0, w0};
        a01 += make_float2(bflo(u0.x), bfhi(u0.x)) * w02;
        a23 += make_float2(bflo(u0.y), bfhi(u0.y)) * w02;
        a45 += make_float2(bflo(u0.z), bfhi(u0.z)) * w02;
        a67 += make_float2(bflo(u0.w), bfhi(u0.w)) * w02;
    }
    float inv = 1.f / sum;
    float4 b0 = ((const float4*)bias)[2 * l16];
    float4 b1 = ((const float4*)bias)[2 * l16 + 1];
    uint4 o;
    o.x = pack_bf16x2(a01.x * inv + b0.x, a01.y * inv + b0.y);
    o.y = pack_bf16x2(a23.x * inv + b0.z, a23.y * inv + b0.w);
    o.z = pack_bf16x2(a45.x * inv + b1.x, a45.y * inv + b1.y);
    o.w = pack_bf16x2(a67.x * inv + b1.z, a67.y * inv + b1.w);
    ((uint4*)(hagg + (size_t)d * 64))[l16] = o;
}

// ---------------------------------------------------------------------------
// BN column sums / sums-of-squares over bf16 [N,128]
// ---------------------------------------------------------------------------
__global__ void k_bnstats(const uint* __restrict__ hagg, int N,
                          float* __restrict__ sums, float* __restrict__ sumsq) {
    int t = threadIdx.x;
    int cg = t & 31, rs = t >> 5;
    float4 s = make_float4(0.f, 0.f, 0.f, 0.f), q = make_float4(0.f, 0.f, 0.f, 0.f);
    for (int n = blockIdx.x * 8 + rs; n < N; n += gridDim.x * 8) {
        uint2 u = ((const uint2*)(hagg + (size_t)n * 64))[cg];
        float v0 = bflo(u.x), v1 = bfhi(u.x), v2 = bflo(u.y), v3 = bfhi(u.y);
        s.x += v0; s.y += v1; s.z += v2; s.w += v3;
        q.x += v0 * v0; q.y += v1 * v1; q.z += v2 * v2; q.w += v3 * v3;
    }
    __shared__ float4 ls[256], lq[256];
    ls[t] = s; lq[t] = q;
    __syncthreads();
    if (t < 32) {
        float4 S = ls[t], Q = lq[t];
        for (int r = 1; r < 8; r++) {
            float4 a = ls[t + r * 32], b = lq[t + r * 32];
            S.x += a.x; S.y += a.y; S.z += a.z; S.w += a.w;
            Q.x += b.x; Q.y += b.y; Q.z += b.z; Q.w += b.w;
        }
        atomicAdd(&sums[t * 4 + 0], S.x);
        atomicAdd(&sums[t * 4 + 1], S.y);
        atomicAdd(&sums[t * 4 + 2], S.z);
        atomicAdd(&sums[t * 4 + 3], S.w);
        atomicAdd(&sumsq[t * 4 + 0], Q.x);
        atomicAdd(&sumsq[t * 4 + 1], Q.y);
        atomicAdd(&sumsq[t * 4 + 2], Q.z);
        atomicAdd(&sumsq[t * 4 + 3], Q.w);
    }
}

// ---------------------------------------------------------------------------
// Per LUT node: BN + ReLU + MLP 128->32 (leaky 0.01) -> 1
// ---------------------------------------------------------------------------
__global__ void k_mlp(const uint* __restrict__ hagg, const int* __restrict__ lut,
                      const float* __restrict__ sums, const float* __restrict__ sumsq,
                      const float* __restrict__ gamma, const float* __restrict__ beta,
                      const float* __restrict__ W1, const float* __restrict__ b1,
                      const float* __restrict__ W2, const float* __restrict__ b2,
                      float* __restrict__ out, int N, int nlut) {
    int blk = blockIdx.x;
    if (blk >= nlut) return;
    int node = lut[blk];
    int lane = threadIdx.x;  // 64
    __shared__ float v[128];
    float invN = 1.f / (float)N;
    uint u = hagg[(size_t)node * 64 + lane];
    int c0 = 2 * lane, c1 = 2 * lane + 1;
    {
        float mean = sums[c0] * invN;
        float var = sumsq[c0] * invN - mean * mean;
        float val = (bflo(u) - mean) / sqrtf(var + 1e-5f) * gamma[c0] + beta[c0];
        v[c0] = fmaxf(val, 0.f);
        mean = sums[c1] * invN;
        var = sumsq[c1] * invN - mean * mean;
        val = (bfhi(u) - mean) / sqrtf(var + 1e-5f) * gamma[c1] + beta[c1];
        v[c1] = fmaxf(val, 0.f);
    }
    __syncthreads();
    float r = 0.f;
    if (lane < 32) {
        float z = b1[lane];
        for (int c = 0; c < 128; c++) z += v[c] * W1[c * 32 + lane];
        z = z > 0.f ? z : 0.01f * z;
        r = z * W2[lane];
    }
#pragma unroll
    for (int off = 16; off >= 1; off >>= 1) r += __shfl_xor(r, off);
    if (lane == 0) out[blk] = r + b2[0];
}

// ---------------------------------------------------------------------------
extern "C" void kernel_launch(void* const* d_in, const int* in_sizes, int n_in,
                              void* d_out, int out_size, void* d_ws, size_t ws_size,
                              hipStream_t stream) {
    const float* x     = (const float*)d_in[0];
    const int*   edges = (const int*)d_in[1];
    const int*   lut   = (const int*)d_in[2];
    const float* W_lin = (const float*)d_in[3];
    const float* att_s = (const float*)d_in[4];
    const float* att_d = (const float*)d_in[5];
    const float* bias  = (const float*)d_in[6];
    const float* gamma = (const float*)d_in[7];
    const float* beta  = (const float*)d_in[8];
    const float* W1    = (const float*)d_in[9];
    const float* b1    = (const float*)d_in[10];
    const float* W2    = (const float*)d_in[11];
    const float* b2    = (const float*)d_in[12];

    int N = in_sizes[0] / 16;
    int E = in_sizes[1] / 2;
    int nlut = in_sizes[2];
    int B = (N + 255) >> BSHIFT;   // 391 for N=100000

    const int* esrc = edges;
    const int* edst = edges + E;

    char* ws = (char*)d_ws;
    size_t off = 0;
    auto alloc = [&](size_t bytes) -> void* {
        void* p = ws + off;
        off += (bytes + 255) & ~(size_t)255;
        return p;
    };
    uint*  h       = (uint*)alloc((size_t)N * 64 * 4);          // bf16x2 [N,128]
    uint*  hagg    = (uint*)alloc((size_t)N * 64 * 4);          // bf16x2 [N,128]
    float* a_src   = (float*)alloc((size_t)N * 4 * 4);
    float* a_dst   = (float*)alloc((size_t)N * 4 * 4);
    int*   offsets = (int*)alloc((size_t)N * 4);
    int*   degs    = (int*)alloc((size_t)N * 4);
    int*   sorted  = (int*)alloc((size_t)B * SORT_CAP * 4);
    uint2* wsorted = (uint2*)alloc((size_t)B * SORT_CAP * 8);   // fp16x4 weights
    uint*  pairs   = (uint*)alloc((size_t)B * SORT_CAP * 4);
    int*   cursor  = (int*)alloc((size_t)NBUCK * 4);
    float* sums    = (float*)alloc(128 * 4);
    float* sumsq   = (float*)alloc(128 * 4);

    k_linear<<<(N + 31) / 32, 256, 0, stream>>>(x, W_lin, att_s, att_d, h,
                                                a_src, a_dst, cursor, sums, sumsq, N);
    kb_scatter<<<(E + TILE - 1) / TILE, SCAT_T, 0, stream>>>(esrc, edst, E, cursor, pairs);
    kb_sort<<<B, SORT_T, 0, stream>>>(pairs, cursor, a_src, a_dst, N,
                                      sorted, wsorted, offsets, degs);
    k_gat<<<(N + 15) / 16, 256, 0, stream>>>(offsets, degs, sorted, wsorted, h,
                                             a_src, a_dst, bias, hagg, N);
    k_bnstats<<<256, 256, 0, stream>>>(hagg, N, sums, sumsq);
    k_mlp<<<nlut, 64, 0, stream>>>(hagg, lut, sums, sumsq, gamma, beta, W1, b1, W2, b2,
                                   (float*)d_out, N, nlut);
}

// Round 8
// 233.942 us; speedup vs baseline: 1.0377x; 1.0377x over previous
//
#include <hip/hip_runtime.h>
#include <hip/hip_fp16.h>
#include <cstdint>
#include <cstring>

typedef unsigned int uint;

#define BSHIFT 8          // 256 nodes per bucket
#define NBUCK 512         // max buckets (N up to 131072)
#define TILE 4096         // kb_scatter tile
#define SCAT_T 512
#define FUSE_T 1024       // fused sort+gat block size
#define SORT_CAP 5120     // per-bucket capacity (mean ~4092, +16 sigma)

__device__ __forceinline__ float leaky02(float x) { return x > 0.f ? x : 0.2f * x; }
__device__ __forceinline__ float bflo(uint u) { return __uint_as_float(u << 16); }
__device__ __forceinline__ float bfhi(uint u) { return __uint_as_float(u & 0xffff0000u); }

__device__ __forceinline__ uint pack_bf16x2(float a, float b) {
    uint ua = __float_as_uint(a), ub = __float_as_uint(b);
    ua += 0x7fffu + ((ua >> 16) & 1u);
    ub += 0x7fffu + ((ub >> 16) & 1u);
    return (ua >> 16) | (ub & 0xffff0000u);
}

__device__ __forceinline__ uint packh2(float a, float b) {
    __half ha = __float2half_rn(a), hb = __float2half_rn(b);
    unsigned short ua, ub;
    memcpy(&ua, &ha, 2);
    memcpy(&ub, &hb, 2);
    return (uint)ua | ((uint)ub << 16);
}

// select half #head (0..3) from a uint2 of 4 packed halves via bit ops
// (no runtime array indexing -> no scratch)
__device__ __forceinline__ float h2f_sel(uint2 xw, int head) {
    uint wrd = (head & 2) ? xw.y : xw.x;
    unsigned short us = (unsigned short)((head & 1) ? (wrd >> 16) : (wrd & 0xffffu));
    __half hh; memcpy(&hh, &us, 2);
    return __half2float(hh);
}

// ---------------------------------------------------------------------------
// Kernel A: h = x @ W_lin (bf16x2); a_src/a_dst via per-block computed 16x4
// Ws/Wd. Block 0 zeroes cursor/sums/sumsq.
// ---------------------------------------------------------------------------
__global__ void k_linear(const float* __restrict__ x, const float* __restrict__ W,
                         const float* __restrict__ att_s, const float* __restrict__ att_d,
                         uint* __restrict__ h, float* __restrict__ a_src,
                         float* __restrict__ a_dst, int* __restrict__ cursor,
                         float* __restrict__ sums, float* __restrict__ sumsq, int N) {
    int tid = threadIdx.x;  // 256
    __shared__ float sx[32][16];
    __shared__ float sWs[64], sWd[64];
    int j = tid & 63;       // channel pair
    int sub = tid >> 6;     // wave id -> node subgroup
    int n0 = blockIdx.x * 32;

    if (blockIdx.x == 0) {
        cursor[tid] = 0; cursor[tid + 256] = 0;
        if (tid < 128) sums[tid] = 0.f;
        else sumsq[tid - 128] = 0.f;
    }

    float2 wreg[16];
#pragma unroll
    for (int k = 0; k < 16; k++) wreg[k] = ((const float2*)(W + k * 128))[j];

    if (tid < 128) {
        int row = tid >> 2;
        if (n0 + row < N)
            ((float4*)sx)[tid] = ((const float4*)(x + (size_t)n0 * 16))[tid];
    } else if (tid < 192) {
        int t = tid - 128;              // t = k*4 + hh
        int k = t >> 2, hh = t & 3;
        float s1 = 0.f, s2 = 0.f;
        for (int c = 0; c < 32; c++) {
            float wv = W[k * 128 + hh * 32 + c];
            s1 += wv * att_s[hh * 32 + c];
            s2 += wv * att_d[hh * 32 + c];
        }
        sWs[t] = s1;
        sWd[t] = s2;
    }
    __syncthreads();

#pragma unroll
    for (int i = 0; i < 8; i++) {
        int loc = sub + i * 4;
        int n = n0 + loc;
        if (n >= N) break;
        float acc0 = 0.f, acc1 = 0.f;
#pragma unroll
        for (int k = 0; k < 16; k++) {
            float xk = sx[loc][k];
            acc0 += xk * wreg[k].x;
            acc1 += xk * wreg[k].y;
        }
        h[(size_t)n * 64 + j] = pack_bf16x2(acc0, acc1);
    }

    int loc2 = tid >> 3, hh = (tid >> 1) & 3, sd = tid & 1;
    int n2 = n0 + loc2;
    if (n2 < N) {
        const float* Wm = sd ? sWd : sWs;
        float acc = 0.f;
#pragma unroll
        for (int k = 0; k < 16; k++) acc += sx[loc2][k] * Wm[k * 4 + hh];
        if (sd) a_dst[n2 * 4 + hh] = acc;
        else    a_src[n2 * 4 + hh] = acc;
    }
}

// ---------------------------------------------------------------------------
// Scatter into capacity buckets: bucket b owns pairs[b*SORT_CAP ...].
// code = (src<<8)|(dst&255).
// ---------------------------------------------------------------------------
__global__ void kb_scatter(const int* __restrict__ src, const int* __restrict__ dst, int E,
                           int* __restrict__ cursor, uint* __restrict__ pairs) {
    __shared__ int tileCnt[NBUCK], tileCnt2[NBUCK], tileOff[NBUCK], gbase[NBUCK];
    __shared__ int wsum[8], wbase[8];
    __shared__ uint lp[TILE];
    __shared__ unsigned short lb[TILE];
    int tid = threadIdx.x;  // 512
    int l = tid & 63, w = tid >> 6;
    int t0 = blockIdx.x * TILE;
    tileCnt[tid] = 0;
    tileCnt2[tid] = 0;
    __syncthreads();
    int dreg[8], sreg[8];
#pragma unroll
    for (int j = 0; j < 8; j++) {
        int idx = t0 + j * SCAT_T + tid;
        if (idx < E) {
            dreg[j] = dst[idx];
            sreg[j] = src[idx];
            atomicAdd(&tileCnt[dreg[j] >> BSHIFT], 1);
        } else dreg[j] = -1;
    }
    __syncthreads();
    int v = tileCnt[tid];
    int s = v;
#pragma unroll
    for (int off = 1; off < 64; off <<= 1) {
        int t = __shfl_up(s, off);
        if (l >= off) s += t;
    }
    if (l == 63) wsum[w] = s;
    __syncthreads();
    if (tid < 8) {
        int b = 0;
        for (int i = 0; i < tid; i++) b += wsum[i];
        wbase[tid] = b;
    }
    __syncthreads();
    int ex = s - v + wbase[w];
    tileOff[tid] = ex;
    if (v > 0) gbase[tid] = atomicAdd(&cursor[tid], v);
    __syncthreads();
#pragma unroll
    for (int j = 0; j < 8; j++) {
        if (dreg[j] >= 0) {
            int bk = dreg[j] >> BSHIFT;
            int r = atomicAdd(&tileCnt2[bk], 1);
            int pos = tileOff[bk] + r;
            lp[pos] = ((uint)sreg[j] << BSHIFT) | (uint)(dreg[j] & 255);
            lb[pos] = (unsigned short)bk;
        }
    }
    __syncthreads();
    int tot = min(TILE, E - t0);
    for (int k = tid; k < tot; k += SCAT_T) {
        int bk = lb[k];
        int lpos = gbase[bk] + (k - tileOff[bk]);
        if (lpos < SORT_CAP)
            pairs[(size_t)bk * SORT_CAP + lpos] = lp[k];
    }
}

// ---------------------------------------------------------------------------
// FUSED per-bucket sort + GAT aggregation (one 1024-thread block per bucket).
// Phase 1: counting sort into LDS lcode + per-edge fp16x4 weights into LDS
//          wlds (no sorted/wsorted global round-trip: saves ~38 MB traffic
//          + one launch + one drain).
// Phase 2: 4 passes x 64 nodes, 16 lanes/node, same gather loop as old k_gat.
//          Different blocks run different phases concurrently -> sort VALU
//          work overlaps other blocks' gather stalls.
// LDS ~71 KB -> 2 blocks/CU.
// ---------------------------------------------------------------------------
__global__ void kb_sortgat(const uint* __restrict__ pairs, const int* __restrict__ cursor,
                           const float* __restrict__ a_src, const float* __restrict__ a_dst,
                           const uint* __restrict__ h, const float* __restrict__ bias,
                           uint* __restrict__ hagg, int N) {
    __shared__ int cnt[256], off0[256], degl[256];
    __shared__ int wsum[4], wbase[4];
    __shared__ uint lcode[SORT_CAP];
    __shared__ uint2 wlds[SORT_CAP];
    __shared__ float4 sad[256], sas[256];
    int tid = threadIdx.x;  // 1024
    int l = tid & 63, w = tid >> 6;
    int b = blockIdx.x;
    int n0 = b << BSHIFT;
    int nn = min(256, N - n0);
    int ebase = b * SORT_CAP;
    int ecnt = cursor[b];
    if (ecnt > SORT_CAP) ecnt = SORT_CAP;
    if (tid < 256) cnt[tid] = 0;
    if (tid < nn) {
        sad[tid] = ((const float4*)a_dst)[n0 + tid];
        sas[tid] = ((const float4*)a_src)[n0 + tid];
    }
    __syncthreads();
    for (int k = tid; k < ecnt; k += FUSE_T)
        atomicAdd(&cnt[pairs[ebase + k] & 255], 1);
    __syncthreads();
    // wave-shfl exclusive scan over 256 entries (waves 0..3)
    int v = (tid < 256) ? cnt[tid] : 0;
    int s = v;
#pragma unroll
    for (int off = 1; off < 64; off <<= 1) {
        int t = __shfl_up(s, off);
        if (l >= off) s += t;
    }
    if (tid < 256 && l == 63) wsum[w] = s;
    __syncthreads();
    if (tid < 4) {
        int base = 0;
        for (int i = 0; i < tid; i++) base += wsum[i];
        wbase[tid] = base;
    }
    __syncthreads();
    if (tid < 256) {
        off0[tid] = s - v + wbase[w];
        degl[tid] = v;
    }
    __syncthreads();
    if (tid < 256) cnt[tid] = 0;
    __syncthreads();
    for (int k = tid; k < ecnt; k += FUSE_T) {
        uint p = pairs[ebase + k];
        int ln = p & 255;
        int r = atomicAdd(&cnt[ln], 1);
        lcode[off0[ln] + r] = p;
    }
    __syncthreads();
    // weight precompute (in-order over lcode, a_src gather is L2-resident)
    for (int k = tid; k < ecnt; k += FUSE_T) {
        uint p = lcode[k];
        int src = (int)(p >> BSHIFT);
        int ln = p & 255;
        float4 as = ((const float4*)a_src)[src];
        float4 ad = sad[ln];
        float w0 = __expf(leaky02(as.x + ad.x));
        float w1 = __expf(leaky02(as.y + ad.y));
        float w2 = __expf(leaky02(as.z + ad.z));
        float w3 = __expf(leaky02(as.w + ad.w));
        wlds[k] = make_uint2(packh2(w0, w1), packh2(w2, w3));
    }
    __syncthreads();
    // aggregation: 16 waves x 4 nodes/wave = 64 nodes per pass, 4 passes
    int q = l >> 4;
    int l16 = l & 15;
    int head = l16 >> 2;
    for (int pass = 0; pass < 4; pass++) {
        int ln = pass * 64 + w * 4 + q;
        if (ln >= nn) continue;   // no __syncthreads below: safe
        int d = n0 + ln;
        int ebs = off0[ln];
        int deg = degl[ln];
        float asv = ((const float*)sas)[ln * 4 + head];
        float adv = ((const float*)sad)[ln * 4 + head];
        float wslf = __expf(leaky02(asv + adv));
        uint4 u = ((const uint4*)(h + (size_t)d * 64))[l16];
        float sum = wslf;
        float2 a01 = make_float2(wslf * bflo(u.x), wslf * bfhi(u.x));
        float2 a23 = make_float2(wslf * bflo(u.y), wslf * bfhi(u.y));
        float2 a45 = make_float2(wslf * bflo(u.z), wslf * bfhi(u.z));
        float2 a67 = make_float2(wslf * bflo(u.w), wslf * bfhi(u.w));

        int i = 0;
        for (; i + 3 < deg; i += 4) {
            uint p0 = lcode[ebs + i];
            uint p1 = lcode[ebs + i + 1];
            uint p2 = lcode[ebs + i + 2];
            uint p3 = lcode[ebs + i + 3];
            uint2 x0 = wlds[ebs + i];
            uint2 x1 = wlds[ebs + i + 1];
            uint2 x2 = wlds[ebs + i + 2];
            uint2 x3 = wlds[ebs + i + 3];
            float w0 = h2f_sel(x0, head);
            float w1 = h2f_sel(x1, head);
            float w2 = h2f_sel(x2, head);
            float w3 = h2f_sel(x3, head);
            uint4 u0 = ((const uint4*)(h + (size_t)(p0 >> BSHIFT) * 64))[l16];
            uint4 u1 = ((const uint4*)(h + (size_t)(p1 >> BSHIFT) * 64))[l16];
            uint4 u2 = ((const uint4*)(h + (size_t)(p2 >> BSHIFT) * 64))[l16];
            uint4 u3 = ((const uint4*)(h + (size_t)(p3 >> BSHIFT) * 64))[l16];
            sum += (w0 + w1) + (w2 + w3);
            float2 w02 = {w0, w0}, w12 = {w1, w1}, w22 = {w2, w2}, w32 = {w3, w3};
            a01 += make_float2(bflo(u0.x), bfhi(u0.x)) * w02
                 + make_float2(bflo(u1.x), bfhi(u1.x)) * w12
                 + make_float2(bflo(u2.x), bfhi(u2.x)) * w22
                 + make_float2(bflo(u3.x), bfhi(u3.x)) * w32;
            a23 += make_float2(bflo(u0.y), bfhi(u0.y)) * w02
                 + make_float2(bflo(u1.y), bfhi(u1.y)) * w12
                 + make_float2(bflo(u2.y), bfhi(u2.y)) * w22
                 + make_float2(bflo(u3.y), bfhi(u3.y)) * w32;
            a45 += make_float2(bflo(u0.z), bfhi(u0.z)) * w02
                 + make_float2(bflo(u1.z), bfhi(u1.z)) * w12
                 + make_float2(bflo(u2.z), bfhi(u2.z)) * w22
                 + make_float2(bflo(u3.z), bfhi(u3.z)) * w32;
            a67 += make_float2(bflo(u0.w), bfhi(u0.w)) * w02
                 + make_float2(bflo(u1.w), bfhi(u1.w)) * w12
                 + make_float2(bflo(u2.w), bfhi(u2.w)) * w22
                 + make_float2(bflo(u3.w), bfhi(u3.w)) * w32;
        }
        for (; i < deg; i++) {
            uint p0 = lcode[ebs + i];
            float w0 = h2f_sel(wlds[ebs + i], head);
            uint4 u0 = ((const uint4*)(h + (size_t)(p0 >> BSHIFT) * 64))[l16];
            sum += w0;
            float2 w02 = {w0, w0};
            a01 += make_float2(bflo(u0.x), bfhi(u0.x)) * w02;
            a23 += make_float2(bflo(u0.y), bfhi(u0.y)) * w02;
            a45 += make_float2(bflo(u0.z), bfhi(u0.z)) * w02;
            a67 += make_float2(bflo(u0.w), bfhi(u0.w)) * w02;
        }
        float inv = 1.f / sum;
        float4 b0 = ((const float4*)bias)[2 * l16];
        float4 b1 = ((const float4*)bias)[2 * l16 + 1];
        uint4 o;
        o.x = pack_bf16x2(a01.x * inv + b0.x, a01.y * inv + b0.y);
        o.y = pack_bf16x2(a23.x * inv + b0.z, a23.y * inv + b0.w);
        o.z = pack_bf16x2(a45.x * inv + b1.x, a45.y * inv + b1.y);
        o.w = pack_bf16x2(a67.x * inv + b1.z, a67.y * inv + b1.w);
        ((uint4*)(hagg + (size_t)d * 64))[l16] = o;
    }
}

// ---------------------------------------------------------------------------
// BN column sums / sums-of-squares over bf16 [N,128]
// ---------------------------------------------------------------------------
__global__ void k_bnstats(const uint* __restrict__ hagg, int N,
                          float* __restrict__ sums, float* __restrict__ sumsq) {
    int t = threadIdx.x;
    int cg = t & 31, rs = t >> 5;
    float4 s = make_float4(0.f, 0.f, 0.f, 0.f), q = make_float4(0.f, 0.f, 0.f, 0.f);
    for (int n = blockIdx.x * 8 + rs; n < N; n += gridDim.x * 8) {
        uint2 u = ((const uint2*)(hagg + (size_t)n * 64))[cg];
        float v0 = bflo(u.x), v1 = bfhi(u.x), v2 = bflo(u.y), v3 = bfhi(u.y);
        s.x += v0; s.y += v1; s.z += v2; s.w += v3;
        q.x += v0 * v0; q.y += v1 * v1; q.z += v2 * v2; q.w += v3 * v3;
    }
    __shared__ float4 ls[256], lq[256];
    ls[t] = s; lq[t] = q;
    __syncthreads();
    if (t < 32) {
        float4 S = ls[t], Q = lq[t];
        for (int r = 1; r < 8; r++) {
            float4 a = ls[t + r * 32], b = lq[t + r * 32];
            S.x += a.x; S.y += a.y; S.z += a.z; S.w += a.w;
            Q.x += b.x; Q.y += b.y; Q.z += b.z; Q.w += b.w;
        }
        atomicAdd(&sums[t * 4 + 0], S.x);
        atomicAdd(&sums[t * 4 + 1], S.y);
        atomicAdd(&sums[t * 4 + 2], S.z);
        atomicAdd(&sums[t * 4 + 3], S.w);
        atomicAdd(&sumsq[t * 4 + 0], Q.x);
        atomicAdd(&sumsq[t * 4 + 1], Q.y);
        atomicAdd(&sumsq[t * 4 + 2], Q.z);
        atomicAdd(&sumsq[t * 4 + 3], Q.w);
    }
}

// ---------------------------------------------------------------------------
// Per LUT node: BN + ReLU + MLP 128->32 (leaky 0.01) -> 1
// ---------------------------------------------------------------------------
__global__ void k_mlp(const uint* __restrict__ hagg, const int* __restrict__ lut,
                      const float* __restrict__ sums, const float* __restrict__ sumsq,
                      const float* __restrict__ gamma, const float* __restrict__ beta,
                      const float* __restrict__ W1, const float* __restrict__ b1,
                      const float* __restrict__ W2, const float* __restrict__ b2,
                      float* __restrict__ out, int N, int nlut) {
    int blk = blockIdx.x;
    if (blk >= nlut) return;
    int node = lut[blk];
    int lane = threadIdx.x;  // 64
    __shared__ float v[128];
    float invN = 1.f / (float)N;
    uint u = hagg[(size_t)node * 64 + lane];
    int c0 = 2 * lane, c1 = 2 * lane + 1;
    {
        float mean = sums[c0] * invN;
        float var = sumsq[c0] * invN - mean * mean;
        float val = (bflo(u) - mean) / sqrtf(var + 1e-5f) * gamma[c0] + beta[c0];
        v[c0] = fmaxf(val, 0.f);
        mean = sums[c1] * invN;
        var = sumsq[c1] * invN - mean * mean;
        val = (bfhi(u) - mean) / sqrtf(var + 1e-5f) * gamma[c1] + beta[c1];
        v[c1] = fmaxf(val, 0.f);
    }
    __syncthreads();
    float r = 0.f;
    if (lane < 32) {
        float z = b1[lane];
        for (int c = 0; c < 128; c++) z += v[c] * W1[c * 32 + lane];
        z = z > 0.f ? z : 0.01f * z;
        r = z * W2[lane];
    }
#pragma unroll
    for (int off = 16; off >= 1; off >>= 1) r += __shfl_xor(r, off);
    if (lane == 0) out[blk] = r + b2[0];
}

// ---------------------------------------------------------------------------
extern "C" void kernel_launch(void* const* d_in, const int* in_sizes, int n_in,
                              void* d_out, int out_size, void* d_ws, size_t ws_size,
                              hipStream_t stream) {
    const float* x     = (const float*)d_in[0];
    const int*   edges = (const int*)d_in[1];
    const int*   lut   = (const int*)d_in[2];
    const float* W_lin = (const float*)d_in[3];
    const float* att_s = (const float*)d_in[4];
    const float* att_d = (const float*)d_in[5];
    const float* bias  = (const float*)d_in[6];
    const float* gamma = (const float*)d_in[7];
    const float* beta  = (const float*)d_in[8];
    const float* W1    = (const float*)d_in[9];
    const float* b1    = (const float*)d_in[10];
    const float* W2    = (const float*)d_in[11];
    const float* b2    = (const float*)d_in[12];

    int N = in_sizes[0] / 16;
    int E = in_sizes[1] / 2;
    int nlut = in_sizes[2];
    int B = (N + 255) >> BSHIFT;   // 391 for N=100000

    const int* esrc = edges;
    const int* edst = edges + E;

    char* ws = (char*)d_ws;
    size_t off = 0;
    auto alloc = [&](size_t bytes) -> void* {
        void* p = ws + off;
        off += (bytes + 255) & ~(size_t)255;
        return p;
    };
    uint*  h       = (uint*)alloc((size_t)N * 64 * 4);          // bf16x2 [N,128]
    uint*  hagg    = (uint*)alloc((size_t)N * 64 * 4);          // bf16x2 [N,128]
    float* a_src   = (float*)alloc((size_t)N * 4 * 4);
    float* a_dst   = (float*)alloc((size_t)N * 4 * 4);
    uint*  pairs   = (uint*)alloc((size_t)B * SORT_CAP * 4);
    int*   cursor  = (int*)alloc((size_t)NBUCK * 4);
    float* sums    = (float*)alloc(128 * 4);
    float* sumsq   = (float*)alloc(128 * 4);

    k_linear<<<(N + 31) / 32, 256, 0, stream>>>(x, W_lin, att_s, att_d, h,
                                                a_src, a_dst, cursor, sums, sumsq, N);
    kb_scatter<<<(E + TILE - 1) / TILE, SCAT_T, 0, stream>>>(esrc, edst, E, cursor, pairs);
    kb_sortgat<<<B, FUSE_T, 0, stream>>>(pairs, cursor, a_src, a_dst, h, bias, hagg, N);
    k_bnstats<<<256, 256, 0, stream>>>(hagg, N, sums, sumsq);
    k_mlp<<<nlut, 64, 0, stream>>>(hagg, lut, sums, sumsq, gamma, beta, W1, b1, W2, b2,
                                   (float*)d_out, N, nlut);
}

// Round 9
// 211.269 us; speedup vs baseline: 1.1490x; 1.1073x over previous
//
#include <hip/hip_runtime.h>
#include <hip/hip_fp16.h>
#include <cstdint>
#include <cstring>

typedef unsigned int uint;

#define BSHIFT 8          // 256 nodes per bucket
#define NBUCK 512         // max buckets (N up to 131072)
#define TILE 4096         // kb_scatter tile
#define SCAT_T 512
#define FUSE_T 1024       // fused sort+gat block size
#define SORT_CAP 5120     // per-bucket capacity (mean ~4092, +16 sigma)

__device__ __forceinline__ float leaky02(float x) { return x > 0.f ? x : 0.2f * x; }
__device__ __forceinline__ float bflo(uint u) { return __uint_as_float(u << 16); }
__device__ __forceinline__ float bfhi(uint u) { return __uint_as_float(u & 0xffff0000u); }

__device__ __forceinline__ uint pack_bf16x2(float a, float b) {
    uint ua = __float_as_uint(a), ub = __float_as_uint(b);
    ua += 0x7fffu + ((ua >> 16) & 1u);
    ub += 0x7fffu + ((ub >> 16) & 1u);
    return (ua >> 16) | (ub & 0xffff0000u);
}

__device__ __forceinline__ uint packh2(float a, float b) {
    __half ha = __float2half_rn(a), hb = __float2half_rn(b);
    unsigned short ua, ub;
    memcpy(&ua, &ha, 2);
    memcpy(&ub, &hb, 2);
    return (uint)ua | ((uint)ub << 16);
}

// select half #head (0..3) from a uint2 of 4 packed halves via bit ops
__device__ __forceinline__ float h2f_sel(uint2 xw, int head) {
    uint wrd = (head & 2) ? xw.y : xw.x;
    unsigned short us = (unsigned short)((head & 1) ? (wrd >> 16) : (wrd & 0xffffu));
    __half hh; memcpy(&hh, &us, 2);
    return __half2float(hh);
}

// ---------------------------------------------------------------------------
// Kernel A: h = x @ W_lin (bf16x2); a_src/a_dst via per-block computed 16x4
// Ws/Wd. Block 0 zeroes cursor/sums/sumsq. Each block zeroes the LUT-flag
// bytes for its 32 nodes (set later by kb_scatter block 0 — stream-ordered).
// ---------------------------------------------------------------------------
__global__ void k_linear(const float* __restrict__ x, const float* __restrict__ W,
                         const float* __restrict__ att_s, const float* __restrict__ att_d,
                         uint* __restrict__ h, float* __restrict__ a_src,
                         float* __restrict__ a_dst, int* __restrict__ cursor,
                         float* __restrict__ sums, float* __restrict__ sumsq,
                         unsigned char* __restrict__ flags, int N) {
    int tid = threadIdx.x;  // 256
    __shared__ float sx[32][16];
    __shared__ float sWs[64], sWd[64];
    int j = tid & 63;       // channel pair
    int sub = tid >> 6;     // wave id -> node subgroup
    int n0 = blockIdx.x * 32;

    if (blockIdx.x == 0) {
        cursor[tid] = 0; cursor[tid + 256] = 0;
        if (tid < 128) sums[tid] = 0.f;
        else sumsq[tid - 128] = 0.f;
    }
    if (tid < 32 && n0 + tid < N) flags[n0 + tid] = 0;

    float2 wreg[16];
#pragma unroll
    for (int k = 0; k < 16; k++) wreg[k] = ((const float2*)(W + k * 128))[j];

    if (tid < 128) {
        int row = tid >> 2;
        if (n0 + row < N)
            ((float4*)sx)[tid] = ((const float4*)(x + (size_t)n0 * 16))[tid];
    } else if (tid < 192) {
        int t = tid - 128;              // t = k*4 + hh
        int k = t >> 2, hh = t & 3;
        float s1 = 0.f, s2 = 0.f;
        for (int c = 0; c < 32; c++) {
            float wv = W[k * 128 + hh * 32 + c];
            s1 += wv * att_s[hh * 32 + c];
            s2 += wv * att_d[hh * 32 + c];
        }
        sWs[t] = s1;
        sWd[t] = s2;
    }
    __syncthreads();

#pragma unroll
    for (int i = 0; i < 8; i++) {
        int loc = sub + i * 4;
        int n = n0 + loc;
        if (n >= N) break;
        float acc0 = 0.f, acc1 = 0.f;
#pragma unroll
        for (int k = 0; k < 16; k++) {
            float xk = sx[loc][k];
            acc0 += xk * wreg[k].x;
            acc1 += xk * wreg[k].y;
        }
        h[(size_t)n * 64 + j] = pack_bf16x2(acc0, acc1);
    }

    int loc2 = tid >> 3, hh = (tid >> 1) & 3, sd = tid & 1;
    int n2 = n0 + loc2;
    if (n2 < N) {
        const float* Wm = sd ? sWd : sWs;
        float acc = 0.f;
#pragma unroll
        for (int k = 0; k < 16; k++) acc += sx[loc2][k] * Wm[k * 4 + hh];
        if (sd) a_dst[n2 * 4 + hh] = acc;
        else    a_src[n2 * 4 + hh] = acc;
    }
}

// ---------------------------------------------------------------------------
// Scatter into capacity buckets: bucket b owns pairs[b*SORT_CAP ...].
// code = (src<<8)|(dst&255). Block 0 also sets LUT flags (flags zeroed by
// k_linear, which completed before this launch).
// ---------------------------------------------------------------------------
__global__ void kb_scatter(const int* __restrict__ src, const int* __restrict__ dst, int E,
                           int* __restrict__ cursor, uint* __restrict__ pairs,
                           const int* __restrict__ lut, int nlut,
                           unsigned char* __restrict__ flags) {
    __shared__ int tileCnt[NBUCK], tileCnt2[NBUCK], tileOff[NBUCK], gbase[NBUCK];
    __shared__ int wsum[8], wbase[8];
    __shared__ uint lp[TILE];
    __shared__ unsigned short lb[TILE];
    int tid = threadIdx.x;  // 512
    int l = tid & 63, w = tid >> 6;
    int t0 = blockIdx.x * TILE;
    if (blockIdx.x == 0) {
        for (int k = tid; k < nlut; k += SCAT_T) flags[lut[k]] = 1;
    }
    tileCnt[tid] = 0;
    tileCnt2[tid] = 0;
    __syncthreads();
    int dreg[8], sreg[8];
#pragma unroll
    for (int j = 0; j < 8; j++) {
        int idx = t0 + j * SCAT_T + tid;
        if (idx < E) {
            dreg[j] = dst[idx];
            sreg[j] = src[idx];
            atomicAdd(&tileCnt[dreg[j] >> BSHIFT], 1);
        } else dreg[j] = -1;
    }
    __syncthreads();
    int v = tileCnt[tid];
    int s = v;
#pragma unroll
    for (int off = 1; off < 64; off <<= 1) {
        int t = __shfl_up(s, off);
        if (l >= off) s += t;
    }
    if (l == 63) wsum[w] = s;
    __syncthreads();
    if (tid < 8) {
        int b = 0;
        for (int i = 0; i < tid; i++) b += wsum[i];
        wbase[tid] = b;
    }
    __syncthreads();
    int ex = s - v + wbase[w];
    tileOff[tid] = ex;
    if (v > 0) gbase[tid] = atomicAdd(&cursor[tid], v);
    __syncthreads();
#pragma unroll
    for (int j = 0; j < 8; j++) {
        if (dreg[j] >= 0) {
            int bk = dreg[j] >> BSHIFT;
            int r = atomicAdd(&tileCnt2[bk], 1);
            int pos = tileOff[bk] + r;
            lp[pos] = ((uint)sreg[j] << BSHIFT) | (uint)(dreg[j] & 255);
            lb[pos] = (unsigned short)bk;
        }
    }
    __syncthreads();
    int tot = min(TILE, E - t0);
    for (int k = tid; k < tot; k += SCAT_T) {
        int bk = lb[k];
        int lpos = gbase[bk] + (k - tileOff[bk]);
        if (lpos < SORT_CAP)
            pairs[(size_t)bk * SORT_CAP + lpos] = lp[k];
    }
}

// ---------------------------------------------------------------------------
// FUSED per-bucket sort + GAT aggregation + BN stats.
//  - counting sort scatters src + fp16x4 weights into LDS in ONE pass
//    (weight computed at scatter time; a_src gather hides under atomics)
//  - aggregation: 4 passes x 64 nodes, 16 lanes/node (8 ch/lane)
//  - BN sums/sumsq accumulated in-register from the fp32 outputs, reduced
//    via shfl + LDS (reusing dead lcode), one atomicAdd/channel/block
//  - hagg store gated on LUT flag: only ~1024 rows are ever read (k_mlp),
//    saves ~25 MB of writes
// ---------------------------------------------------------------------------
__global__ void __launch_bounds__(1024, 8) kb_sortgat(
                           const uint* __restrict__ pairs, const int* __restrict__ cursor,
                           const float* __restrict__ a_src, const float* __restrict__ a_dst,
                           const uint* __restrict__ h, const float* __restrict__ bias,
                           const unsigned char* __restrict__ flags,
                           uint* __restrict__ hagg,
                           float* __restrict__ sums, float* __restrict__ sumsq, int N) {
    __shared__ int cnt[256], off0[256], degl[256];
    __shared__ int wsum[4], wbase[4];
    __shared__ uint lcode[SORT_CAP];      // src per edge; reused as BN-reduce buf
    __shared__ uint2 wlds[SORT_CAP];      // fp16x4 weights per edge
    __shared__ float4 sad[256];
    int tid = threadIdx.x;  // 1024
    int l = tid & 63, w = tid >> 6;
    int b = blockIdx.x;
    int n0 = b << BSHIFT;
    int nn = min(256, N - n0);
    int ebase = b * SORT_CAP;
    int ecnt = cursor[b];
    if (ecnt > SORT_CAP) ecnt = SORT_CAP;
    if (tid < 256) cnt[tid] = 0;
    if (tid < nn) sad[tid] = ((const float4*)a_dst)[n0 + tid];
    __syncthreads();
    for (int k = tid; k < ecnt; k += FUSE_T)
        atomicAdd(&cnt[pairs[ebase + k] & 255], 1);
    __syncthreads();
    // wave-shfl exclusive scan over 256 entries (waves 0..3)
    int v = (tid < 256) ? cnt[tid] : 0;
    int s = v;
#pragma unroll
    for (int off = 1; off < 64; off <<= 1) {
        int t = __shfl_up(s, off);
        if (l >= off) s += t;
    }
    if (tid < 256 && l == 63) wsum[w] = s;
    __syncthreads();
    if (tid < 4) {
        int base = 0;
        for (int i = 0; i < tid; i++) base += wsum[i];
        wbase[tid] = base;
    }
    __syncthreads();
    if (tid < 256) {
        off0[tid] = s - v + wbase[w];
        degl[tid] = v;
    }
    __syncthreads();
    if (tid < 256) cnt[tid] = 0;
    __syncthreads();
    // single pass: scatter src + compute weights (a_src is L2-resident)
    for (int k = tid; k < ecnt; k += FUSE_T) {
        uint p = pairs[ebase + k];
        int ln = p & 255;
        int src = (int)(p >> BSHIFT);
        int r = atomicAdd(&cnt[ln], 1);
        int pos = off0[ln] + r;
        lcode[pos] = (uint)src;
        float4 as = ((const float4*)a_src)[src];
        float4 ad = sad[ln];
        wlds[pos] = make_uint2(
            packh2(__expf(leaky02(as.x + ad.x)), __expf(leaky02(as.y + ad.y))),
            packh2(__expf(leaky02(as.z + ad.z)), __expf(leaky02(as.w + ad.w))));
    }
    __syncthreads();
    // aggregation: 16 waves x 4 nodes/wave = 64 nodes per pass, 4 passes
    int q = l >> 4;
    int l16 = l & 15;
    int head = l16 >> 2;
    float4 b0 = ((const float4*)bias)[2 * l16];
    float4 b1 = ((const float4*)bias)[2 * l16 + 1];
    float sv[8], sq[8];
#pragma unroll
    for (int j = 0; j < 8; j++) { sv[j] = 0.f; sq[j] = 0.f; }
    for (int pass = 0; pass < 4; pass++) {
        int ln = pass * 64 + w * 4 + q;
        if (ln >= nn) continue;   // no barriers below in this loop: safe
        int d = n0 + ln;
        int ebs = off0[ln];
        int deg = degl[ln];
        float asv = a_src[d * 4 + head];
        float adv = ((const float*)sad)[ln * 4 + head];
        float wslf = __expf(leaky02(asv + adv));
        uint4 u = ((const uint4*)(h + (size_t)d * 64))[l16];
        float sum = wslf;
        float2 a01 = make_float2(wslf * bflo(u.x), wslf * bfhi(u.x));
        float2 a23 = make_float2(wslf * bflo(u.y), wslf * bfhi(u.y));
        float2 a45 = make_float2(wslf * bflo(u.z), wslf * bfhi(u.z));
        float2 a67 = make_float2(wslf * bflo(u.w), wslf * bfhi(u.w));

        int i = 0;
        for (; i + 3 < deg; i += 4) {
            uint p0 = lcode[ebs + i];
            uint p1 = lcode[ebs + i + 1];
            uint p2 = lcode[ebs + i + 2];
            uint p3 = lcode[ebs + i + 3];
            uint2 x0 = wlds[ebs + i];
            uint2 x1 = wlds[ebs + i + 1];
            uint2 x2 = wlds[ebs + i + 2];
            uint2 x3 = wlds[ebs + i + 3];
            float w0 = h2f_sel(x0, head);
            float w1 = h2f_sel(x1, head);
            float w2 = h2f_sel(x2, head);
            float w3 = h2f_sel(x3, head);
            uint4 u0 = ((const uint4*)(h + (size_t)p0 * 64))[l16];
            uint4 u1 = ((const uint4*)(h + (size_t)p1 * 64))[l16];
            uint4 u2 = ((const uint4*)(h + (size_t)p2 * 64))[l16];
            uint4 u3 = ((const uint4*)(h + (size_t)p3 * 64))[l16];
            sum += (w0 + w1) + (w2 + w3);
            float2 w02 = {w0, w0}, w12 = {w1, w1}, w22 = {w2, w2}, w32 = {w3, w3};
            a01 += make_float2(bflo(u0.x), bfhi(u0.x)) * w02
                 + make_float2(bflo(u1.x), bfhi(u1.x)) * w12
                 + make_float2(bflo(u2.x), bfhi(u2.x)) * w22
                 + make_float2(bflo(u3.x), bfhi(u3.x)) * w32;
            a23 += make_float2(bflo(u0.y), bfhi(u0.y)) * w02
                 + make_float2(bflo(u1.y), bfhi(u1.y)) * w12
                 + make_float2(bflo(u2.y), bfhi(u2.y)) * w22
                 + make_float2(bflo(u3.y), bfhi(u3.y)) * w32;
            a45 += make_float2(bflo(u0.z), bfhi(u0.z)) * w02
                 + make_float2(bflo(u1.z), bfhi(u1.z)) * w12
                 + make_float2(bflo(u2.z), bfhi(u2.z)) * w22
                 + make_float2(bflo(u3.z), bfhi(u3.z)) * w32;
            a67 += make_float2(bflo(u0.w), bfhi(u0.w)) * w02
                 + make_float2(bflo(u1.w), bfhi(u1.w)) * w12
                 + make_float2(bflo(u2.w), bfhi(u2.w)) * w22
                 + make_float2(bflo(u3.w), bfhi(u3.w)) * w32;
        }
        for (; i < deg; i++) {
            uint p0 = lcode[ebs + i];
            float w0 = h2f_sel(wlds[ebs + i], head);
            uint4 u0 = ((const uint4*)(h + (size_t)p0 * 64))[l16];
            sum += w0;
            float2 w02 = {w0, w0};
            a01 += make_float2(bflo(u0.x), bfhi(u0.x)) * w02;
            a23 += make_float2(bflo(u0.y), bfhi(u0.y)) * w02;
            a45 += make_float2(bflo(u0.z), bfhi(u0.z)) * w02;
            a67 += make_float2(bflo(u0.w), bfhi(u0.w)) * w02;
        }
        float inv = 1.f / sum;
        float v0 = a01.x * inv + b0.x;
        float v1 = a01.y * inv + b0.y;
        float v2 = a23.x * inv + b0.z;
        float v3 = a23.y * inv + b0.w;
        float v4 = a45.x * inv + b1.x;
        float v5 = a45.y * inv + b1.y;
        float v6 = a67.x * inv + b1.z;
        float v7 = a67.y * inv + b1.w;
        sv[0] += v0; sq[0] += v0 * v0;
        sv[1] += v1; sq[1] += v1 * v1;
        sv[2] += v2; sq[2] += v2 * v2;
        sv[3] += v3; sq[3] += v3 * v3;
        sv[4] += v4; sq[4] += v4 * v4;
        sv[5] += v5; sq[5] += v5 * v5;
        sv[6] += v6; sq[6] += v6 * v6;
        sv[7] += v7; sq[7] += v7 * v7;
        if (flags[d]) {
            uint4 o;
            o.x = pack_bf16x2(v0, v1);
            o.y = pack_bf16x2(v2, v3);
            o.z = pack_bf16x2(v4, v5);
            o.w = pack_bf16x2(v6, v7);
            ((uint4*)(hagg + (size_t)d * 64))[l16] = o;
        }
    }
    // BN stats reduction: shfl over node-groups (lane bits 4,5), then LDS
    __syncthreads();               // all lcode/wlds reads done -> reuse lcode
#pragma unroll
    for (int j = 0; j < 8; j++) {
        sv[j] += __shfl_xor(sv[j], 16);
        sv[j] += __shfl_xor(sv[j], 32);
        sq[j] += __shfl_xor(sq[j], 16);
        sq[j] += __shfl_xor(sq[j], 32);
    }
    float* red = (float*)lcode;    // 256 rows x 16 floats = 16 KB <= 20 KB
    if (l < 16) {
#pragma unroll
        for (int j = 0; j < 8; j++) {
            red[(w * 16 + l) * 16 + j] = sv[j];
            red[(w * 16 + l) * 16 + 8 + j] = sq[j];
        }
    }
    __syncthreads();
    if (tid < 256) {
        int lg = tid >> 4, j = tid & 15;
        float tot = 0.f;
#pragma unroll
        for (int ww = 0; ww < 16; ww++) tot += red[(ww * 16 + lg) * 16 + j];
        if (j < 8) atomicAdd(&sums[lg * 8 + j], tot);
        else       atomicAdd(&sumsq[lg * 8 + j - 8], tot);
    }
}

// ---------------------------------------------------------------------------
// Per LUT node: BN + ReLU + MLP 128->32 (leaky 0.01) -> 1
// ---------------------------------------------------------------------------
__global__ void k_mlp(const uint* __restrict__ hagg, const int* __restrict__ lut,
                      const float* __restrict__ sums, const float* __restrict__ sumsq,
                      const float* __restrict__ gamma, const float* __restrict__ beta,
                      const float* __restrict__ W1, const float* __restrict__ b1,
                      const float* __restrict__ W2, const float* __restrict__ b2,
                      float* __restrict__ out, int N, int nlut) {
    int blk = blockIdx.x;
    if (blk >= nlut) return;
    int node = lut[blk];
    int lane = threadIdx.x;  // 64
    __shared__ float v[128];
    float invN = 1.f / (float)N;
    uint u = hagg[(size_t)node * 64 + lane];
    int c0 = 2 * lane, c1 = 2 * lane + 1;
    {
        float mean = sums[c0] * invN;
        float var = sumsq[c0] * invN - mean * mean;
        float val = (bflo(u) - mean) / sqrtf(var + 1e-5f) * gamma[c0] + beta[c0];
        v[c0] = fmaxf(val, 0.f);
        mean = sums[c1] * invN;
        var = sumsq[c1] * invN - mean * mean;
        val = (bfhi(u) - mean) / sqrtf(var + 1e-5f) * gamma[c1] + beta[c1];
        v[c1] = fmaxf(val, 0.f);
    }
    __syncthreads();
    float r = 0.f;
    if (lane < 32) {
        float z = b1[lane];
        for (int c = 0; c < 128; c++) z += v[c] * W1[c * 32 + lane];
        z = z > 0.f ? z : 0.01f * z;
        r = z * W2[lane];
    }
#pragma unroll
    for (int off = 16; off >= 1; off >>= 1) r += __shfl_xor(r, off);
    if (lane == 0) out[blk] = r + b2[0];
}

// ---------------------------------------------------------------------------
extern "C" void kernel_launch(void* const* d_in, const int* in_sizes, int n_in,
                              void* d_out, int out_size, void* d_ws, size_t ws_size,
                              hipStream_t stream) {
    const float* x     = (const float*)d_in[0];
    const int*   edges = (const int*)d_in[1];
    const int*   lut   = (const int*)d_in[2];
    const float* W_lin = (const float*)d_in[3];
    const float* att_s = (const float*)d_in[4];
    const float* att_d = (const float*)d_in[5];
    const float* bias  = (const float*)d_in[6];
    const float* gamma = (const float*)d_in[7];
    const float* beta  = (const float*)d_in[8];
    const float* W1    = (const float*)d_in[9];
    const float* b1    = (const float*)d_in[10];
    const float* W2    = (const float*)d_in[11];
    const float* b2    = (const float*)d_in[12];

    int N = in_sizes[0] / 16;
    int E = in_sizes[1] / 2;
    int nlut = in_sizes[2];
    int B = (N + 255) >> BSHIFT;   // 391 for N=100000

    const int* esrc = edges;
    const int* edst = edges + E;

    char* ws = (char*)d_ws;
    size_t off = 0;
    auto alloc = [&](size_t bytes) -> void* {
        void* p = ws + off;
        off += (bytes + 255) & ~(size_t)255;
        return p;
    };
    uint*  h       = (uint*)alloc((size_t)N * 64 * 4);          // bf16x2 [N,128]
    uint*  hagg    = (uint*)alloc((size_t)N * 64 * 4);          // bf16x2 [N,128]
    float* a_src   = (float*)alloc((size_t)N * 4 * 4);
    float* a_dst   = (float*)alloc((size_t)N * 4 * 4);
    uint*  pairs   = (uint*)alloc((size_t)B * SORT_CAP * 4);
    int*   cursor  = (int*)alloc((size_t)NBUCK * 4);
    float* sums    = (float*)alloc(128 * 4);
    float* sumsq   = (float*)alloc(128 * 4);
    unsigned char* flags = (unsigned char*)alloc((size_t)N);

    k_linear<<<(N + 31) / 32, 256, 0, stream>>>(x, W_lin, att_s, att_d, h,
                                                a_src, a_dst, cursor, sums, sumsq,
                                                flags, N);
    kb_scatter<<<(E + TILE - 1) / TILE, SCAT_T, 0, stream>>>(esrc, edst, E, cursor, pairs,
                                                             lut, nlut, flags);
    kb_sortgat<<<B, FUSE_T, 0, stream>>>(pairs, cursor, a_src, a_dst, h, bias,
                                         flags, hagg, sums, sumsq, N);
    k_mlp<<<nlut, 64, 0, stream>>>(hagg, lut, sums, sumsq, gamma, beta, W1, b1, W2, b2,
                                   (float*)d_out, N, nlut);
}

// Round 10
// 205.025 us; speedup vs baseline: 1.1840x; 1.0305x over previous
//
#include <hip/hip_runtime.h>
#include <hip/hip_fp16.h>
#include <cstdint>
#include <cstring>

typedef unsigned int uint;

#define BSHIFT 8          // 256 nodes per bucket
#define NBUCK 512         // max buckets (N up to 131072)
#define TILE 4096         // kb_scatter tile
#define SCAT_T 512
#define FUSE_T 1024       // fused sort+gat block size
#define SORT_CAP 5120     // per-bucket capacity (mean ~4092, +16 sigma)

__device__ __forceinline__ float leaky02(float x) { return x > 0.f ? x : 0.2f * x; }
__device__ __forceinline__ float bflo(uint u) { return __uint_as_float(u << 16); }
__device__ __forceinline__ float bfhi(uint u) { return __uint_as_float(u & 0xffff0000u); }

__device__ __forceinline__ uint pack_bf16x2(float a, float b) {
    uint ua = __float_as_uint(a), ub = __float_as_uint(b);
    ua += 0x7fffu + ((ua >> 16) & 1u);
    ub += 0x7fffu + ((ub >> 16) & 1u);
    return (ua >> 16) | (ub & 0xffff0000u);
}

__device__ __forceinline__ uint packh2(float a, float b) {
    __half ha = __float2half_rn(a), hb = __float2half_rn(b);
    unsigned short ua, ub;
    memcpy(&ua, &ha, 2);
    memcpy(&ub, &hb, 2);
    return (uint)ua | ((uint)ub << 16);
}

// select half #head (0..3) from a uint2 of 4 packed halves via bit ops
__device__ __forceinline__ float h2f_sel(uint2 xw, int head) {
    uint wrd = (head & 2) ? xw.y : xw.x;
    unsigned short us = (unsigned short)((head & 1) ? (wrd >> 16) : (wrd & 0xffffu));
    __half hh; memcpy(&hh, &us, 2);
    return __half2float(hh);
}

// ---------------------------------------------------------------------------
// Kernel A: h = x @ W_lin (bf16x2); a_src/a_dst via per-block computed 16x4
// Ws/Wd. Block 0 zeroes cursor/sums/sumsq. Each block zeroes the LUT-flag
// bytes for its 32 nodes (set later by kb_scatter block 0 — stream-ordered).
// ---------------------------------------------------------------------------
__global__ void k_linear(const float* __restrict__ x, const float* __restrict__ W,
                         const float* __restrict__ att_s, const float* __restrict__ att_d,
                         uint* __restrict__ h, float* __restrict__ a_src,
                         float* __restrict__ a_dst, int* __restrict__ cursor,
                         float* __restrict__ sums, float* __restrict__ sumsq,
                         unsigned char* __restrict__ flags, int N) {
    int tid = threadIdx.x;  // 256
    __shared__ float sx[32][16];
    __shared__ float sWs[64], sWd[64];
    int j = tid & 63;       // channel pair
    int sub = tid >> 6;     // wave id -> node subgroup
    int n0 = blockIdx.x * 32;

    if (blockIdx.x == 0) {
        cursor[tid] = 0; cursor[tid + 256] = 0;
        if (tid < 128) sums[tid] = 0.f;
        else sumsq[tid - 128] = 0.f;
    }
    if (tid < 32 && n0 + tid < N) flags[n0 + tid] = 0;

    float2 wreg[16];
#pragma unroll
    for (int k = 0; k < 16; k++) wreg[k] = ((const float2*)(W + k * 128))[j];

    if (tid < 128) {
        int row = tid >> 2;
        if (n0 + row < N)
            ((float4*)sx)[tid] = ((const float4*)(x + (size_t)n0 * 16))[tid];
    } else if (tid < 192) {
        int t = tid - 128;              // t = k*4 + hh
        int k = t >> 2, hh = t & 3;
        float s1 = 0.f, s2 = 0.f;
        for (int c = 0; c < 32; c++) {
            float wv = W[k * 128 + hh * 32 + c];
            s1 += wv * att_s[hh * 32 + c];
            s2 += wv * att_d[hh * 32 + c];
        }
        sWs[t] = s1;
        sWd[t] = s2;
    }
    __syncthreads();

#pragma unroll
    for (int i = 0; i < 8; i++) {
        int loc = sub + i * 4;
        int n = n0 + loc;
        if (n >= N) break;
        float acc0 = 0.f, acc1 = 0.f;
#pragma unroll
        for (int k = 0; k < 16; k++) {
            float xk = sx[loc][k];
            acc0 += xk * wreg[k].x;
            acc1 += xk * wreg[k].y;
        }
        h[(size_t)n * 64 + j] = pack_bf16x2(acc0, acc1);
    }

    int loc2 = tid >> 3, hh = (tid >> 1) & 3, sd = tid & 1;
    int n2 = n0 + loc2;
    if (n2 < N) {
        const float* Wm = sd ? sWd : sWs;
        float acc = 0.f;
#pragma unroll
        for (int k = 0; k < 16; k++) acc += sx[loc2][k] * Wm[k * 4 + hh];
        if (sd) a_dst[n2 * 4 + hh] = acc;
        else    a_src[n2 * 4 + hh] = acc;
    }
}

// ---------------------------------------------------------------------------
// Scatter into capacity buckets: bucket b owns pairs[b*SORT_CAP ...].
// code = (src<<8)|(dst&255). Block 0 also sets LUT flags (flags zeroed by
// k_linear, which completed before this launch).
// ---------------------------------------------------------------------------
__global__ void kb_scatter(const int* __restrict__ src, const int* __restrict__ dst, int E,
                           int* __restrict__ cursor, uint* __restrict__ pairs,
                           const int* __restrict__ lut, int nlut,
                           unsigned char* __restrict__ flags) {
    __shared__ int tileCnt[NBUCK], tileCnt2[NBUCK], tileOff[NBUCK], gbase[NBUCK];
    __shared__ int wsum[8], wbase[8];
    __shared__ uint lp[TILE];
    __shared__ unsigned short lb[TILE];
    int tid = threadIdx.x;  // 512
    int l = tid & 63, w = tid >> 6;
    int t0 = blockIdx.x * TILE;
    if (blockIdx.x == 0) {
        for (int k = tid; k < nlut; k += SCAT_T) flags[lut[k]] = 1;
    }
    tileCnt[tid] = 0;
    tileCnt2[tid] = 0;
    __syncthreads();
    int dreg[8], sreg[8];
#pragma unroll
    for (int j = 0; j < 8; j++) {
        int idx = t0 + j * SCAT_T + tid;
        if (idx < E) {
            dreg[j] = dst[idx];
            sreg[j] = src[idx];
            atomicAdd(&tileCnt[dreg[j] >> BSHIFT], 1);
        } else dreg[j] = -1;
    }
    __syncthreads();
    int v = tileCnt[tid];
    int s = v;
#pragma unroll
    for (int off = 1; off < 64; off <<= 1) {
        int t = __shfl_up(s, off);
        if (l >= off) s += t;
    }
    if (l == 63) wsum[w] = s;
    __syncthreads();
    if (tid < 8) {
        int b = 0;
        for (int i = 0; i < tid; i++) b += wsum[i];
        wbase[tid] = b;
    }
    __syncthreads();
    int ex = s - v + wbase[w];
    tileOff[tid] = ex;
    if (v > 0) gbase[tid] = atomicAdd(&cursor[tid], v);
    __syncthreads();
#pragma unroll
    for (int j = 0; j < 8; j++) {
        if (dreg[j] >= 0) {
            int bk = dreg[j] >> BSHIFT;
            int r = atomicAdd(&tileCnt2[bk], 1);
            int pos = tileOff[bk] + r;
            lp[pos] = ((uint)sreg[j] << BSHIFT) | (uint)(dreg[j] & 255);
            lb[pos] = (unsigned short)bk;
        }
    }
    __syncthreads();
    int tot = min(TILE, E - t0);
    for (int k = tid; k < tot; k += SCAT_T) {
        int bk = lb[k];
        int lpos = gbase[bk] + (k - tileOff[bk]);
        if (lpos < SORT_CAP)
            pairs[(size_t)bk * SORT_CAP + lpos] = lp[k];
    }
}

// ---------------------------------------------------------------------------
// FUSED per-bucket sort + GAT aggregation + BN stats.
// launch_bounds(1024, 4): VGPR cap 128. The (1024, 8) variant capped VGPRs
// at 64 and SPILLED the 16 BN accumulator floats to scratch (R9: VGPR=32,
// FETCH/WRITE +30/+30 MB symmetric, dur +15 us). Occupancy was ~1 block/CU
// anyway (53%), so the cap relaxation costs nothing.
// ---------------------------------------------------------------------------
__global__ void __launch_bounds__(1024, 4) kb_sortgat(
                           const uint* __restrict__ pairs, const int* __restrict__ cursor,
                           const float* __restrict__ a_src, const float* __restrict__ a_dst,
                           const uint* __restrict__ h, const float* __restrict__ bias,
                           const unsigned char* __restrict__ flags,
                           uint* __restrict__ hagg,
                           float* __restrict__ sums, float* __restrict__ sumsq, int N) {
    __shared__ int cnt[256], off0[256], degl[256];
    __shared__ int wsum[4], wbase[4];
    __shared__ uint lcode[SORT_CAP];      // src per edge; reused as BN-reduce buf
    __shared__ uint2 wlds[SORT_CAP];      // fp16x4 weights per edge
    __shared__ float4 sad[256];
    int tid = threadIdx.x;  // 1024
    int l = tid & 63, w = tid >> 6;
    int b = blockIdx.x;
    int n0 = b << BSHIFT;
    int nn = min(256, N - n0);
    int ebase = b * SORT_CAP;
    int ecnt = cursor[b];
    if (ecnt > SORT_CAP) ecnt = SORT_CAP;
    if (tid < 256) cnt[tid] = 0;
    if (tid < nn) sad[tid] = ((const float4*)a_dst)[n0 + tid];
    __syncthreads();
    for (int k = tid; k < ecnt; k += FUSE_T)
        atomicAdd(&cnt[pairs[ebase + k] & 255], 1);
    __syncthreads();
    // wave-shfl exclusive scan over 256 entries (waves 0..3)
    int v = (tid < 256) ? cnt[tid] : 0;
    int s = v;
#pragma unroll
    for (int off = 1; off < 64; off <<= 1) {
        int t = __shfl_up(s, off);
        if (l >= off) s += t;
    }
    if (tid < 256 && l == 63) wsum[w] = s;
    __syncthreads();
    if (tid < 4) {
        int base = 0;
        for (int i = 0; i < tid; i++) base += wsum[i];
        wbase[tid] = base;
    }
    __syncthreads();
    if (tid < 256) {
        off0[tid] = s - v + wbase[w];
        degl[tid] = v;
    }
    __syncthreads();
    if (tid < 256) cnt[tid] = 0;
    __syncthreads();
    // single pass: scatter src + compute weights (a_src is L2-resident)
    for (int k = tid; k < ecnt; k += FUSE_T) {
        uint p = pairs[ebase + k];
        int ln = p & 255;
        int src = (int)(p >> BSHIFT);
        int r = atomicAdd(&cnt[ln], 1);
        int pos = off0[ln] + r;
        lcode[pos] = (uint)src;
        float4 as = ((const float4*)a_src)[src];
        float4 ad = sad[ln];
        wlds[pos] = make_uint2(
            packh2(__expf(leaky02(as.x + ad.x)), __expf(leaky02(as.y + ad.y))),
            packh2(__expf(leaky02(as.z + ad.z)), __expf(leaky02(as.w + ad.w))));
    }
    __syncthreads();
    // aggregation: 16 waves x 4 nodes/wave = 64 nodes per pass, 4 passes
    int q = l >> 4;
    int l16 = l & 15;
    int head = l16 >> 2;
    float4 b0 = ((const float4*)bias)[2 * l16];
    float4 b1 = ((const float4*)bias)[2 * l16 + 1];
    float sv[8], sq[8];
#pragma unroll
    for (int j = 0; j < 8; j++) { sv[j] = 0.f; sq[j] = 0.f; }
    for (int pass = 0; pass < 4; pass++) {
        int ln = pass * 64 + w * 4 + q;
        if (ln >= nn) continue;   // no barriers below in this loop: safe
        int d = n0 + ln;
        int ebs = off0[ln];
        int deg = degl[ln];
        float asv = a_src[d * 4 + head];
        float adv = ((const float*)sad)[ln * 4 + head];
        float wslf = __expf(leaky02(asv + adv));
        uint4 u = ((const uint4*)(h + (size_t)d * 64))[l16];
        float sum = wslf;
        float2 a01 = make_float2(wslf * bflo(u.x), wslf * bfhi(u.x));
        float2 a23 = make_float2(wslf * bflo(u.y), wslf * bfhi(u.y));
        float2 a45 = make_float2(wslf * bflo(u.z), wslf * bfhi(u.z));
        float2 a67 = make_float2(wslf * bflo(u.w), wslf * bfhi(u.w));

        int i = 0;
        for (; i + 3 < deg; i += 4) {
            uint p0 = lcode[ebs + i];
            uint p1 = lcode[ebs + i + 1];
            uint p2 = lcode[ebs + i + 2];
            uint p3 = lcode[ebs + i + 3];
            uint2 x0 = wlds[ebs + i];
            uint2 x1 = wlds[ebs + i + 1];
            uint2 x2 = wlds[ebs + i + 2];
            uint2 x3 = wlds[ebs + i + 3];
            float w0 = h2f_sel(x0, head);
            float w1 = h2f_sel(x1, head);
            float w2 = h2f_sel(x2, head);
            float w3 = h2f_sel(x3, head);
            uint4 u0 = ((const uint4*)(h + (size_t)p0 * 64))[l16];
            uint4 u1 = ((const uint4*)(h + (size_t)p1 * 64))[l16];
            uint4 u2 = ((const uint4*)(h + (size_t)p2 * 64))[l16];
            uint4 u3 = ((const uint4*)(h + (size_t)p3 * 64))[l16];
            sum += (w0 + w1) + (w2 + w3);
            float2 w02 = {w0, w0}, w12 = {w1, w1}, w22 = {w2, w2}, w32 = {w3, w3};
            a01 += make_float2(bflo(u0.x), bfhi(u0.x)) * w02
                 + make_float2(bflo(u1.x), bfhi(u1.x)) * w12
                 + make_float2(bflo(u2.x), bfhi(u2.x)) * w22
                 + make_float2(bflo(u3.x), bfhi(u3.x)) * w32;
            a23 += make_float2(bflo(u0.y), bfhi(u0.y)) * w02
                 + make_float2(bflo(u1.y), bfhi(u1.y)) * w12
                 + make_float2(bflo(u2.y), bfhi(u2.y)) * w22
                 + make_float2(bflo(u3.y), bfhi(u3.y)) * w32;
            a45 += make_float2(bflo(u0.z), bfhi(u0.z)) * w02
                 + make_float2(bflo(u1.z), bfhi(u1.z)) * w12
                 + make_float2(bflo(u2.z), bfhi(u2.z)) * w22
                 + make_float2(bflo(u3.z), bfhi(u3.z)) * w32;
            a67 += make_float2(bflo(u0.w), bfhi(u0.w)) * w02
                 + make_float2(bflo(u1.w), bfhi(u1.w)) * w12
                 + make_float2(bflo(u2.w), bfhi(u2.w)) * w22
                 + make_float2(bflo(u3.w), bfhi(u3.w)) * w32;
        }
        for (; i < deg; i++) {
            uint p0 = lcode[ebs + i];
            float w0 = h2f_sel(wlds[ebs + i], head);
            uint4 u0 = ((const uint4*)(h + (size_t)p0 * 64))[l16];
            sum += w0;
            float2 w02 = {w0, w0};
            a01 += make_float2(bflo(u0.x), bfhi(u0.x)) * w02;
            a23 += make_float2(bflo(u0.y), bfhi(u0.y)) * w02;
            a45 += make_float2(bflo(u0.z), bfhi(u0.z)) * w02;
            a67 += make_float2(bflo(u0.w), bfhi(u0.w)) * w02;
        }
        float inv = 1.f / sum;
        float v0 = a01.x * inv + b0.x;
        float v1 = a01.y * inv + b0.y;
        float v2 = a23.x * inv + b0.z;
        float v3 = a23.y * inv + b0.w;
        float v4 = a45.x * inv + b1.x;
        float v5 = a45.y * inv + b1.y;
        float v6 = a67.x * inv + b1.z;
        float v7 = a67.y * inv + b1.w;
        sv[0] += v0; sq[0] += v0 * v0;
        sv[1] += v1; sq[1] += v1 * v1;
        sv[2] += v2; sq[2] += v2 * v2;
        sv[3] += v3; sq[3] += v3 * v3;
        sv[4] += v4; sq[4] += v4 * v4;
        sv[5] += v5; sq[5] += v5 * v5;
        sv[6] += v6; sq[6] += v6 * v6;
        sv[7] += v7; sq[7] += v7 * v7;
        if (flags[d]) {
            uint4 o;
            o.x = pack_bf16x2(v0, v1);
            o.y = pack_bf16x2(v2, v3);
            o.z = pack_bf16x2(v4, v5);
            o.w = pack_bf16x2(v6, v7);
            ((uint4*)(hagg + (size_t)d * 64))[l16] = o;
        }
    }
    // BN stats reduction: shfl over node-groups (lane bits 4,5), then LDS
    __syncthreads();               // all lcode/wlds reads done -> reuse lcode
#pragma unroll
    for (int j = 0; j < 8; j++) {
        sv[j] += __shfl_xor(sv[j], 16);
        sv[j] += __shfl_xor(sv[j], 32);
        sq[j] += __shfl_xor(sq[j], 16);
        sq[j] += __shfl_xor(sq[j], 32);
    }
    float* red = (float*)lcode;    // 256 rows x 16 floats = 16 KB <= 20 KB
    if (l < 16) {
#pragma unroll
        for (int j = 0; j < 8; j++) {
            red[(w * 16 + l) * 16 + j] = sv[j];
            red[(w * 16 + l) * 16 + 8 + j] = sq[j];
        }
    }
    __syncthreads();
    if (tid < 256) {
        int lg = tid >> 4, j = tid & 15;
        float tot = 0.f;
#pragma unroll
        for (int ww = 0; ww < 16; ww++) tot += red[(ww * 16 + lg) * 16 + j];
        if (j < 8) atomicAdd(&sums[lg * 8 + j], tot);
        else       atomicAdd(&sumsq[lg * 8 + j - 8], tot);
    }
}

// ---------------------------------------------------------------------------
// Per LUT node: BN + ReLU + MLP 128->32 (leaky 0.01) -> 1
// ---------------------------------------------------------------------------
__global__ void k_mlp(const uint* __restrict__ hagg, const int* __restrict__ lut,
                      const float* __restrict__ sums, const float* __restrict__ sumsq,
                      const float* __restrict__ gamma, const float* __restrict__ beta,
                      const float* __restrict__ W1, const float* __restrict__ b1,
                      const float* __restrict__ W2, const float* __restrict__ b2,
                      float* __restrict__ out, int N, int nlut) {
    int blk = blockIdx.x;
    if (blk >= nlut) return;
    int node = lut[blk];
    int lane = threadIdx.x;  // 64
    __shared__ float v[128];
    float invN = 1.f / (float)N;
    uint u = hagg[(size_t)node * 64 + lane];
    int c0 = 2 * lane, c1 = 2 * lane + 1;
    {
        float mean = sums[c0] * invN;
        float var = sumsq[c0] * invN - mean * mean;
        float val = (bflo(u) - mean) / sqrtf(var + 1e-5f) * gamma[c0] + beta[c0];
        v[c0] = fmaxf(val, 0.f);
        mean = sums[c1] * invN;
        var = sumsq[c1] * invN - mean * mean;
        val = (bfhi(u) - mean) / sqrtf(var + 1e-5f) * gamma[c1] + beta[c1];
        v[c1] = fmaxf(val, 0.f);
    }
    __syncthreads();
    float r = 0.f;
    if (lane < 32) {
        float z = b1[lane];
        for (int c = 0; c < 128; c++) z += v[c] * W1[c * 32 + lane];
        z = z > 0.f ? z : 0.01f * z;
        r = z * W2[lane];
    }
#pragma unroll
    for (int off = 16; off >= 1; off >>= 1) r += __shfl_xor(r, off);
    if (lane == 0) out[blk] = r + b2[0];
}

// ---------------------------------------------------------------------------
extern "C" void kernel_launch(void* const* d_in, const int* in_sizes, int n_in,
                              void* d_out, int out_size, void* d_ws, size_t ws_size,
                              hipStream_t stream) {
    const float* x     = (const float*)d_in[0];
    const int*   edges = (const int*)d_in[1];
    const int*   lut   = (const int*)d_in[2];
    const float* W_lin = (const float*)d_in[3];
    const float* att_s = (const float*)d_in[4];
    const float* att_d = (const float*)d_in[5];
    const float* bias  = (const float*)d_in[6];
    const float* gamma = (const float*)d_in[7];
    const float* beta  = (const float*)d_in[8];
    const float* W1    = (const float*)d_in[9];
    const float* b1    = (const float*)d_in[10];
    const float* W2    = (const float*)d_in[11];
    const float* b2    = (const float*)d_in[12];

    int N = in_sizes[0] / 16;
    int E = in_sizes[1] / 2;
    int nlut = in_sizes[2];
    int B = (N + 255) >> BSHIFT;   // 391 for N=100000

    const int* esrc = edges;
    const int* edst = edges + E;

    char* ws = (char*)d_ws;
    size_t off = 0;
    auto alloc = [&](size_t bytes) -> void* {
        void* p = ws + off;
        off += (bytes + 255) & ~(size_t)255;
        return p;
    };
    uint*  h       = (uint*)alloc((size_t)N * 64 * 4);          // bf16x2 [N,128]
    uint*  hagg    = (uint*)alloc((size_t)N * 64 * 4);          // bf16x2 [N,128]
    float* a_src   = (float*)alloc((size_t)N * 4 * 4);
    float* a_dst   = (float*)alloc((size_t)N * 4 * 4);
    uint*  pairs   = (uint*)alloc((size_t)B * SORT_CAP * 4);
    int*   cursor  = (int*)alloc((size_t)NBUCK * 4);
    float* sums    = (float*)alloc(128 * 4);
    float* sumsq   = (float*)alloc(128 * 4);
    unsigned char* flags = (unsigned char*)alloc((size_t)N);

    k_linear<<<(N + 31) / 32, 256, 0, stream>>>(x, W_lin, att_s, att_d, h,
                                                a_src, a_dst, cursor, sums, sumsq,
                                                flags, N);
    kb_scatter<<<(E + TILE - 1) / TILE, SCAT_T, 0, stream>>>(esrc, edst, E, cursor, pairs,
                                                             lut, nlut, flags);
    kb_sortgat<<<B, FUSE_T, 0, stream>>>(pairs, cursor, a_src, a_dst, h, bias,
                                         flags, hagg, sums, sumsq, N);
    k_mlp<<<nlut, 64, 0, stream>>>(hagg, lut, sums, sumsq, gamma, beta, W1, b1, W2, b2,
                                   (float*)d_out, N, nlut);
}

// Round 11
// 190.498 us; speedup vs baseline: 1.2743x; 1.0763x over previous
//
#include <hip/hip_runtime.h>
#include <hip/hip_fp16.h>
#include <cstdint>
#include <cstring>

typedef unsigned int uint;

#define BSHIFT 8          // 256 nodes per bucket
#define NBUCK 512         // max buckets (N up to 131072)
#define TILE 4096         // scatter tile
#define FUSE_T 1024       // fused sort+gat block size
#define LS_T 512          // fused linear+scatter block size
#define SORT_CAP 5120     // per-bucket capacity (mean ~4092, +16 sigma)

__device__ __forceinline__ float leaky02(float x) { return x > 0.f ? x : 0.2f * x; }
__device__ __forceinline__ float bflo(uint u) { return __uint_as_float(u << 16); }
__device__ __forceinline__ float bfhi(uint u) { return __uint_as_float(u & 0xffff0000u); }

__device__ __forceinline__ uint pack_bf16x2(float a, float b) {
    uint ua = __float_as_uint(a), ub = __float_as_uint(b);
    ua += 0x7fffu + ((ua >> 16) & 1u);
    ub += 0x7fffu + ((ub >> 16) & 1u);
    return (ua >> 16) | (ub & 0xffff0000u);
}

__device__ __forceinline__ uint packh2(float a, float b) {
    __half ha = __float2half_rn(a), hb = __float2half_rn(b);
    unsigned short ua, ub;
    memcpy(&ua, &ha, 2);
    memcpy(&ub, &hb, 2);
    return (uint)ua | ((uint)ub << 16);
}

// select half #head (0..3) from a uint2 of 4 packed halves via bit ops
__device__ __forceinline__ float h2f_sel(uint2 xw, int head) {
    uint wrd = (head & 2) ? xw.y : xw.x;
    unsigned short us = (unsigned short)((head & 1) ? (wrd >> 16) : (wrd & 0xffffu));
    __half hh; memcpy(&hh, &us, 2);
    return __half2float(hh);
}

// ---------------------------------------------------------------------------
// FUSED k_linear + kb_scatter (independent work, block-range split).
// Blocks [0, Lb): linear — 64 nodes/block, 512 threads.
// Blocks [Lb, Lb+Sb): scatter — one 4096-edge tile/block, 512 threads.
// cursor/sums/sumsq/flags are zeroed by a hipMemsetAsync before this launch.
// ---------------------------------------------------------------------------
__global__ void k_linscat(const float* __restrict__ x, const float* __restrict__ W,
                          const float* __restrict__ att_s, const float* __restrict__ att_d,
                          uint* __restrict__ h, float* __restrict__ a_src,
                          float* __restrict__ a_dst,
                          const int* __restrict__ src, const int* __restrict__ dst, int E,
                          int* __restrict__ cursor, uint* __restrict__ pairs,
                          const int* __restrict__ lut, int nlut,
                          unsigned char* __restrict__ flags, int N, int Lb) {
    int tid = threadIdx.x;  // 512
    if (blockIdx.x < Lb) {
        // ---------------- linear part: 64 nodes ----------------
        __shared__ float sx[64][16];
        __shared__ float sWs[64], sWd[64];
        int j = tid & 63;       // channel pair
        int sub = tid >> 6;     // wave id 0..7 -> node subgroup
        int n0 = blockIdx.x * 64;

        float2 wreg[16];
#pragma unroll
        for (int k = 0; k < 16; k++) wreg[k] = ((const float2*)(W + k * 128))[j];

        if (tid < 256) {
            int row = tid >> 2;
            if (n0 + row < N)
                ((float4*)sx)[tid] = ((const float4*)(x + (size_t)n0 * 16))[tid];
        } else if (tid < 320) {
            int t = tid - 256;              // t = k*4 + hh
            int k = t >> 2, hh = t & 3;
            float s1 = 0.f, s2 = 0.f;
            for (int c = 0; c < 32; c++) {
                float wv = W[k * 128 + hh * 32 + c];
                s1 += wv * att_s[hh * 32 + c];
                s2 += wv * att_d[hh * 32 + c];
            }
            sWs[t] = s1;
            sWd[t] = s2;
        }
        __syncthreads();

#pragma unroll
        for (int i = 0; i < 8; i++) {
            int loc = sub + i * 8;
            int n = n0 + loc;
            if (n >= N) break;
            float acc0 = 0.f, acc1 = 0.f;
#pragma unroll
            for (int k = 0; k < 16; k++) {
                float xk = sx[loc][k];
                acc0 += xk * wreg[k].x;
                acc1 += xk * wreg[k].y;
            }
            h[(size_t)n * 64 + j] = pack_bf16x2(acc0, acc1);
        }

        // a_src / a_dst: thread t -> (node tid>>3, head (tid>>1)&3, sd tid&1)
        int loc2 = tid >> 3, hh = (tid >> 1) & 3, sd = tid & 1;
        int n2 = n0 + loc2;
        if (n2 < N) {
            const float* Wm = sd ? sWd : sWs;
            float acc = 0.f;
#pragma unroll
            for (int k = 0; k < 16; k++) acc += sx[loc2][k] * Wm[k * 4 + hh];
            if (sd) a_dst[n2 * 4 + hh] = acc;
            else    a_src[n2 * 4 + hh] = acc;
        }
    } else {
        // ---------------- scatter part: one 4096-edge tile ----------------
        __shared__ int tileCnt[NBUCK], tileCnt2[NBUCK], tileOff[NBUCK], gbase[NBUCK];
        __shared__ int wsum[8], wbase[8];
        __shared__ uint lp[TILE];
        __shared__ unsigned short lb[TILE];
        int bid = blockIdx.x - Lb;
        int l = tid & 63, w = tid >> 6;
        int t0 = bid * TILE;
        if (bid == 0) {
            for (int k = tid; k < nlut; k += LS_T) flags[lut[k]] = 1;
        }
        tileCnt[tid] = 0;
        tileCnt2[tid] = 0;
        __syncthreads();
        int dreg[8], sreg[8];
#pragma unroll
        for (int jj = 0; jj < 8; jj++) {
            int idx = t0 + jj * LS_T + tid;
            if (idx < E) {
                dreg[jj] = dst[idx];
                sreg[jj] = src[idx];
                atomicAdd(&tileCnt[dreg[jj] >> BSHIFT], 1);
            } else dreg[jj] = -1;
        }
        __syncthreads();
        int v = tileCnt[tid];
        int s = v;
#pragma unroll
        for (int off = 1; off < 64; off <<= 1) {
            int t = __shfl_up(s, off);
            if (l >= off) s += t;
        }
        if (l == 63) wsum[w] = s;
        __syncthreads();
        if (tid < 8) {
            int b = 0;
            for (int i = 0; i < tid; i++) b += wsum[i];
            wbase[tid] = b;
        }
        __syncthreads();
        int ex = s - v + wbase[w];
        tileOff[tid] = ex;
        if (v > 0) gbase[tid] = atomicAdd(&cursor[tid], v);
        __syncthreads();
#pragma unroll
        for (int jj = 0; jj < 8; jj++) {
            if (dreg[jj] >= 0) {
                int bk = dreg[jj] >> BSHIFT;
                int r = atomicAdd(&tileCnt2[bk], 1);
                int pos = tileOff[bk] + r;
                lp[pos] = ((uint)sreg[jj] << BSHIFT) | (uint)(dreg[jj] & 255);
                lb[pos] = (unsigned short)bk;
            }
        }
        __syncthreads();
        int tot = min(TILE, E - t0);
        for (int k = tid; k < tot; k += LS_T) {
            int bk = lb[k];
            int lpos = gbase[bk] + (k - tileOff[bk]);
            if (lpos < SORT_CAP)
                pairs[(size_t)bk * SORT_CAP + lpos] = lp[k];
        }
    }
}

// ---------------------------------------------------------------------------
// FUSED per-bucket sort + GAT aggregation + BN stats.
// launch_bounds(1024, 8): VGPR cap 64 -> 2 blocks/CU (LDS 69KB x2 <= 160KB),
// all 391 blocks co-resident in ONE round (R10's (1024,4) exceeded 64 VGPR ->
// 1 block/CU -> 2-round schedule, occupancy 33%, BW 2.5 TB/s).
// To fit 64 without R9's spill: aggregation unroll 4->2 (same outstanding
// gathers per CU: 32 waves x2 vs 16 waves x4) and bias via LDS after loop.
// ---------------------------------------------------------------------------
__global__ void __launch_bounds__(1024, 8) kb_sortgat(
                           const uint* __restrict__ pairs, const int* __restrict__ cursor,
                           const float* __restrict__ a_src, const float* __restrict__ a_dst,
                           const uint* __restrict__ h, const float* __restrict__ bias,
                           const unsigned char* __restrict__ flags,
                           uint* __restrict__ hagg,
                           float* __restrict__ sums, float* __restrict__ sumsq, int N) {
    __shared__ int cnt[256], off0[256], degl[256];
    __shared__ int wsum[4], wbase[4];
    __shared__ uint lcode[SORT_CAP];      // src per edge; reused as BN-reduce buf
    __shared__ uint2 wlds[SORT_CAP];      // fp16x4 weights per edge
    __shared__ float4 sad[256];
    __shared__ float4 sbias[32];
    int tid = threadIdx.x;  // 1024
    int l = tid & 63, w = tid >> 6;
    int b = blockIdx.x;
    int n0 = b << BSHIFT;
    int nn = min(256, N - n0);
    int ebase = b * SORT_CAP;
    int ecnt = cursor[b];
    if (ecnt > SORT_CAP) ecnt = SORT_CAP;
    if (tid < 256) cnt[tid] = 0;
    if (tid < nn) sad[tid] = ((const float4*)a_dst)[n0 + tid];
    if (tid >= 992) sbias[tid - 992] = ((const float4*)bias)[tid - 992];
    __syncthreads();
    for (int k = tid; k < ecnt; k += FUSE_T)
        atomicAdd(&cnt[pairs[ebase + k] & 255], 1);
    __syncthreads();
    // wave-shfl exclusive scan over 256 entries (waves 0..3)
    int v = (tid < 256) ? cnt[tid] : 0;
    int s = v;
#pragma unroll
    for (int off = 1; off < 64; off <<= 1) {
        int t = __shfl_up(s, off);
        if (l >= off) s += t;
    }
    if (tid < 256 && l == 63) wsum[w] = s;
    __syncthreads();
    if (tid < 4) {
        int base = 0;
        for (int i = 0; i < tid; i++) base += wsum[i];
        wbase[tid] = base;
    }
    __syncthreads();
    if (tid < 256) {
        off0[tid] = s - v + wbase[w];
        degl[tid] = v;
    }
    __syncthreads();
    if (tid < 256) cnt[tid] = 0;
    __syncthreads();
    // single pass: scatter src + compute weights (a_src is L2-resident)
    for (int k = tid; k < ecnt; k += FUSE_T) {
        uint p = pairs[ebase + k];
        int ln = p & 255;
        int src = (int)(p >> BSHIFT);
        int r = atomicAdd(&cnt[ln], 1);
        int pos = off0[ln] + r;
        lcode[pos] = (uint)src;
        float4 as = ((const float4*)a_src)[src];
        float4 ad = sad[ln];
        wlds[pos] = make_uint2(
            packh2(__expf(leaky02(as.x + ad.x)), __expf(leaky02(as.y + ad.y))),
            packh2(__expf(leaky02(as.z + ad.z)), __expf(leaky02(as.w + ad.w))));
    }
    __syncthreads();
    // aggregation: 16 waves x 4 nodes/wave = 64 nodes per pass, 4 passes
    int q = l >> 4;
    int l16 = l & 15;
    int head = l16 >> 2;
    float sv[8], sq[8];
#pragma unroll
    for (int j = 0; j < 8; j++) { sv[j] = 0.f; sq[j] = 0.f; }
    for (int pass = 0; pass < 4; pass++) {
        int ln = pass * 64 + w * 4 + q;
        if (ln >= nn) continue;   // no barriers below in this loop: safe
        int d = n0 + ln;
        int ebs = off0[ln];
        int deg = degl[ln];
        float asv = a_src[d * 4 + head];
        float adv = ((const float*)sad)[ln * 4 + head];
        float wslf = __expf(leaky02(asv + adv));
        uint4 u = ((const uint4*)(h + (size_t)d * 64))[l16];
        float sum = wslf;
        float2 a01 = make_float2(wslf * bflo(u.x), wslf * bfhi(u.x));
        float2 a23 = make_float2(wslf * bflo(u.y), wslf * bfhi(u.y));
        float2 a45 = make_float2(wslf * bflo(u.z), wslf * bfhi(u.z));
        float2 a67 = make_float2(wslf * bflo(u.w), wslf * bfhi(u.w));

        int i = 0;
        for (; i + 1 < deg; i += 2) {
            uint p0 = lcode[ebs + i];
            uint p1 = lcode[ebs + i + 1];
            float w0 = h2f_sel(wlds[ebs + i], head);
            float w1 = h2f_sel(wlds[ebs + i + 1], head);
            uint4 u0 = ((const uint4*)(h + (size_t)p0 * 64))[l16];
            uint4 u1 = ((const uint4*)(h + (size_t)p1 * 64))[l16];
            sum += w0 + w1;
            float2 w02 = {w0, w0}, w12 = {w1, w1};
            a01 += make_float2(bflo(u0.x), bfhi(u0.x)) * w02
                 + make_float2(bflo(u1.x), bfhi(u1.x)) * w12;
            a23 += make_float2(bflo(u0.y), bfhi(u0.y)) * w02
                 + make_float2(bflo(u1.y), bfhi(u1.y)) * w12;
            a45 += make_float2(bflo(u0.z), bfhi(u0.z)) * w02
                 + make_float2(bflo(u1.z), bfhi(u1.z)) * w12;
            a67 += make_float2(bflo(u0.w), bfhi(u0.w)) * w02
                 + make_float2(bflo(u1.w), bfhi(u1.w)) * w12;
        }
        if (i < deg) {
            uint p0 = lcode[ebs + i];
            float w0 = h2f_sel(wlds[ebs + i], head);
            uint4 u0 = ((const uint4*)(h + (size_t)p0 * 64))[l16];
            sum += w0;
            float2 w02 = {w0, w0};
            a01 += make_float2(bflo(u0.x), bfhi(u0.x)) * w02;
            a23 += make_float2(bflo(u0.y), bfhi(u0.y)) * w02;
            a45 += make_float2(bflo(u0.z), bfhi(u0.z)) * w02;
            a67 += make_float2(bflo(u0.w), bfhi(u0.w)) * w02;
        }
        float inv = 1.f / sum;
        float4 b0 = sbias[2 * l16];
        float4 b1 = sbias[2 * l16 + 1];
        float v0 = a01.x * inv + b0.x;
        float v1 = a01.y * inv + b0.y;
        float v2 = a23.x * inv + b0.z;
        float v3 = a23.y * inv + b0.w;
        float v4 = a45.x * inv + b1.x;
        float v5 = a45.y * inv + b1.y;
        float v6 = a67.x * inv + b1.z;
        float v7 = a67.y * inv + b1.w;
        sv[0] += v0; sq[0] += v0 * v0;
        sv[1] += v1; sq[1] += v1 * v1;
        sv[2] += v2; sq[2] += v2 * v2;
        sv[3] += v3; sq[3] += v3 * v3;
        sv[4] += v4; sq[4] += v4 * v4;
        sv[5] += v5; sq[5] += v5 * v5;
        sv[6] += v6; sq[6] += v6 * v6;
        sv[7] += v7; sq[7] += v7 * v7;
        if (flags[d]) {
            uint4 o;
            o.x = pack_bf16x2(v0, v1);
            o.y = pack_bf16x2(v2, v3);
            o.z = pack_bf16x2(v4, v5);
            o.w = pack_bf16x2(v6, v7);
            ((uint4*)(hagg + (size_t)d * 64))[l16] = o;
        }
    }
    // BN stats reduction: shfl over node-groups (lane bits 4,5), then LDS
    __syncthreads();               // all lcode/wlds reads done -> reuse lcode
#pragma unroll
    for (int j = 0; j < 8; j++) {
        sv[j] += __shfl_xor(sv[j], 16);
        sv[j] += __shfl_xor(sv[j], 32);
        sq[j] += __shfl_xor(sq[j], 16);
        sq[j] += __shfl_xor(sq[j], 32);
    }
    float* red = (float*)lcode;    // 256 rows x 16 floats = 16 KB <= 20 KB
    if (l < 16) {
#pragma unroll
        for (int j = 0; j < 8; j++) {
            red[(w * 16 + l) * 16 + j] = sv[j];
            red[(w * 16 + l) * 16 + 8 + j] = sq[j];
        }
    }
    __syncthreads();
    if (tid < 256) {
        int lg = tid >> 4, j = tid & 15;
        float tot = 0.f;
#pragma unroll
        for (int ww = 0; ww < 16; ww++) tot += red[(ww * 16 + lg) * 16 + j];
        if (j < 8) atomicAdd(&sums[lg * 8 + j], tot);
        else       atomicAdd(&sumsq[lg * 8 + j - 8], tot);
    }
}

// ---------------------------------------------------------------------------
// Per LUT node: BN + ReLU + MLP 128->32 (leaky 0.01) -> 1
// ---------------------------------------------------------------------------
__global__ void k_mlp(const uint* __restrict__ hagg, const int* __restrict__ lut,
                      const float* __restrict__ sums, const float* __restrict__ sumsq,
                      const float* __restrict__ gamma, const float* __restrict__ beta,
                      const float* __restrict__ W1, const float* __restrict__ b1,
                      const float* __restrict__ W2, const float* __restrict__ b2,
                      float* __restrict__ out, int N, int nlut) {
    int blk = blockIdx.x;
    if (blk >= nlut) return;
    int node = lut[blk];
    int lane = threadIdx.x;  // 64
    __shared__ float v[128];
    float invN = 1.f / (float)N;
    uint u = hagg[(size_t)node * 64 + lane];
    int c0 = 2 * lane, c1 = 2 * lane + 1;
    {
        float mean = sums[c0] * invN;
        float var = sumsq[c0] * invN - mean * mean;
        float val = (bflo(u) - mean) / sqrtf(var + 1e-5f) * gamma[c0] + beta[c0];
        v[c0] = fmaxf(val, 0.f);
        mean = sums[c1] * invN;
        var = sumsq[c1] * invN - mean * mean;
        val = (bfhi(u) - mean) / sqrtf(var + 1e-5f) * gamma[c1] + beta[c1];
        v[c1] = fmaxf(val, 0.f);
    }
    __syncthreads();
    float r = 0.f;
    if (lane < 32) {
        float z = b1[lane];
        for (int c = 0; c < 128; c++) z += v[c] * W1[c * 32 + lane];
        z = z > 0.f ? z : 0.01f * z;
        r = z * W2[lane];
    }
#pragma unroll
    for (int off = 16; off >= 1; off >>= 1) r += __shfl_xor(r, off);
    if (lane == 0) out[blk] = r + b2[0];
}

// ---------------------------------------------------------------------------
extern "C" void kernel_launch(void* const* d_in, const int* in_sizes, int n_in,
                              void* d_out, int out_size, void* d_ws, size_t ws_size,
                              hipStream_t stream) {
    const float* x     = (const float*)d_in[0];
    const int*   edges = (const int*)d_in[1];
    const int*   lut   = (const int*)d_in[2];
    const float* W_lin = (const float*)d_in[3];
    const float* att_s = (const float*)d_in[4];
    const float* att_d = (const float*)d_in[5];
    const float* bias  = (const float*)d_in[6];
    const float* gamma = (const float*)d_in[7];
    const float* beta  = (const float*)d_in[8];
    const float* W1    = (const float*)d_in[9];
    const float* b1    = (const float*)d_in[10];
    const float* W2    = (const float*)d_in[11];
    const float* b2    = (const float*)d_in[12];

    int N = in_sizes[0] / 16;
    int E = in_sizes[1] / 2;
    int nlut = in_sizes[2];
    int B = (N + 255) >> BSHIFT;   // 391 for N=100000
    int Lb = (N + 63) / 64;        // linear blocks (64 nodes each)
    int Sb = (E + TILE - 1) / TILE;

    const int* esrc = edges;
    const int* edst = edges + E;

    char* ws = (char*)d_ws;
    size_t off = 0;
    auto alloc = [&](size_t bytes) -> void* {
        void* p = ws + off;
        off += (bytes + 255) & ~(size_t)255;
        return p;
    };
    uint*  h       = (uint*)alloc((size_t)N * 64 * 4);          // bf16x2 [N,128]
    uint*  hagg    = (uint*)alloc((size_t)N * 64 * 4);          // bf16x2 [N,128]
    float* a_src   = (float*)alloc((size_t)N * 4 * 4);
    float* a_dst   = (float*)alloc((size_t)N * 4 * 4);
    uint*  pairs   = (uint*)alloc((size_t)B * SORT_CAP * 4);
    // contiguous zero-region: cursor | sums | sumsq | flags
    char*  zbase   = ws + off;
    int*   cursor  = (int*)alloc((size_t)NBUCK * 4);
    float* sums    = (float*)alloc(128 * 4);
    float* sumsq   = (float*)alloc(128 * 4);
    unsigned char* flags = (unsigned char*)alloc((size_t)N);
    size_t zspan = (size_t)((ws + off) - zbase);

    hipMemsetAsync(zbase, 0, zspan, stream);
    k_linscat<<<Lb + Sb, LS_T, 0, stream>>>(x, W_lin, att_s, att_d, h, a_src, a_dst,
                                            esrc, edst, E, cursor, pairs,
                                            lut, nlut, flags, N, Lb);
    kb_sortgat<<<B, FUSE_T, 0, stream>>>(pairs, cursor, a_src, a_dst, h, bias,
                                         flags, hagg, sums, sumsq, N);
    k_mlp<<<nlut, 64, 0, stream>>>(hagg, lut, sums, sumsq, gamma, beta, W1, b1, W2, b2,
                                   (float*)d_out, N, nlut);
}